// Round 1
// baseline (617.838 us; speedup 1.0000x reference)
//
#include <hip/hip_runtime.h>
#include <hip/hip_bf16.h>
#include <cstddef>

// ---------------- setup kernels ----------------

__global__ __launch_bounds__(256) void k_init_deg(int* __restrict__ ideg, int n) {
    int i = blockIdx.x * 256 + threadIdx.x;
    if (i < n) ideg[i] = 1;  // self-loop
}

__global__ __launch_bounds__(256) void k_count(const int* __restrict__ dst, int* __restrict__ ideg, int e) {
    int i = blockIdx.x * 256 + threadIdx.x;
    if (i < e) atomicAdd(&ideg[dst[i]], 1);
}

__global__ __launch_bounds__(256) void k_dinv(const int* __restrict__ ideg, float* __restrict__ dinv, int n) {
    int i = blockIdx.x * 256 + threadIdx.x;
    if (i < n) dinv[i] = rsqrtf((float)ideg[i]);
}

// block-wise inclusive scan (256/block), writes block-local exclusive into rowptr, block sums to bsum
__global__ __launch_bounds__(256) void k_scan_a(const int* __restrict__ cnt, int* __restrict__ rowptr,
                                                int* __restrict__ bsum, int n) {
    __shared__ int sh[256];
    int t = threadIdx.x;
    int i = blockIdx.x * 256 + t;
    int v = (i < n) ? cnt[i] : 0;
    sh[t] = v;
    __syncthreads();
    for (int off = 1; off < 256; off <<= 1) {
        int x = (t >= off) ? sh[t - off] : 0;
        __syncthreads();
        sh[t] += x;
        __syncthreads();
    }
    if (i < n) rowptr[i] = sh[t] - v;          // block-local exclusive
    if (t == 255) bsum[blockIdx.x] = sh[255];  // block total
}

// single-block scan of block sums -> bbase (exclusive); writes rowptr[n] = grand total
__global__ __launch_bounds__(256) void k_scan_b(const int* __restrict__ bsum, int* __restrict__ bbase,
                                                int nb, int* __restrict__ rowptr, int n) {
    __shared__ int sh[256];
    int t = threadIdx.x;
    int v = (t < nb) ? bsum[t] : 0;
    sh[t] = v;
    __syncthreads();
    for (int off = 1; off < 256; off <<= 1) {
        int x = (t >= off) ? sh[t - off] : 0;
        __syncthreads();
        sh[t] += x;
        __syncthreads();
    }
    if (t < nb) bbase[t] = sh[t] - v;
    if (t == 255) rowptr[n] = sh[255];
}

__global__ __launch_bounds__(256) void k_scan_c(int* __restrict__ rowptr, const int* __restrict__ bbase,
                                                int* __restrict__ cursor, int n) {
    int i = blockIdx.x * 256 + threadIdx.x;
    if (i < n) {
        int r = rowptr[i] + bbase[i >> 8];
        rowptr[i] = r;
        cursor[i] = r;
    }
}

// scatter edges (and self-loops) into CSR sorted by dst
__global__ __launch_bounds__(256) void k_fill(const int* __restrict__ src, const int* __restrict__ dst,
                                              const float* __restrict__ dinv, int* __restrict__ cursor,
                                              int* __restrict__ csr_s, float* __restrict__ csr_w,
                                              int e, int n) {
    int i = blockIdx.x * 256 + threadIdx.x;
    if (i >= e + n) return;
    int s, d;
    if (i < e) { s = src[i]; d = dst[i]; }
    else       { s = i - e; d = s; }
    int pos = atomicAdd(&cursor[d], 1);
    csr_s[pos] = s;
    csr_w[pos] = dinv[s] * dinv[d];
}

// ---------------- dense GEMM: O[n x 128] = H[n x 128] @ W[128 x 128] ----------------
// block = 256 threads, tile = 64 rows x 128 cols, per-thread 4x8
__global__ __launch_bounds__(256) void k_gemm(const float* __restrict__ H, const float* __restrict__ W,
                                              float* __restrict__ O, int nrows) {
    __shared__ float Wl[128 * 128];
    __shared__ float Hl[64][132];
    const int t = threadIdx.x;
    const int row0 = blockIdx.x * 64;

#pragma unroll
    for (int i = 0; i < 16; ++i) {
        int idx = (t + i * 256) * 4;
        *(float4*)&Wl[idx] = *(const float4*)&W[idx];
    }
#pragma unroll
    for (int i = 0; i < 8; ++i) {
        int idx = t + i * 256;       // float4 index within 64x128 tile
        int r = idx >> 5;            // /32 float4s per row
        int c = (idx & 31) << 2;
        float4 v;
        if (row0 + r < nrows) v = *(const float4*)&H[(size_t)(row0 + r) * 128 + c];
        else                  v = make_float4(0.f, 0.f, 0.f, 0.f);
        *(float4*)&Hl[r][c] = v;
    }
    __syncthreads();

    const int ct = t & 15, rt = t >> 4;
    const int c0 = ct * 8, r0 = rt * 4;
    float acc[4][8];
#pragma unroll
    for (int i = 0; i < 4; ++i)
#pragma unroll
        for (int j = 0; j < 8; ++j) acc[i][j] = 0.f;

#pragma unroll 4
    for (int k = 0; k < 128; ++k) {
        float4 w0 = *(float4*)&Wl[k * 128 + c0];
        float4 w1 = *(float4*)&Wl[k * 128 + c0 + 4];
        float wv[8] = {w0.x, w0.y, w0.z, w0.w, w1.x, w1.y, w1.z, w1.w};
        float hv[4] = {Hl[r0 + 0][k], Hl[r0 + 1][k], Hl[r0 + 2][k], Hl[r0 + 3][k]};
#pragma unroll
        for (int i = 0; i < 4; ++i)
#pragma unroll
            for (int j = 0; j < 8; ++j) acc[i][j] = fmaf(hv[i], wv[j], acc[i][j]);
    }

#pragma unroll
    for (int i = 0; i < 4; ++i) {
        int r = row0 + r0 + i;
        if (r < nrows) {
            float4 o0 = make_float4(acc[i][0], acc[i][1], acc[i][2], acc[i][3]);
            float4 o1 = make_float4(acc[i][4], acc[i][5], acc[i][6], acc[i][7]);
            *(float4*)&O[(size_t)r * 128 + c0]     = o0;
            *(float4*)&O[(size_t)r * 128 + c0 + 4] = o1;
        }
    }
}

// ---------------- aggregation: Hn[v] = relu(sum_e w[e]*XW[src[e]] + bias), CSR by dst ----------------
// one 64-lane wave per node, lane handles features (2*lane, 2*lane+1)
__global__ __launch_bounds__(256) void k_agg(const float* __restrict__ XW, const int* __restrict__ cs,
                                             const float* __restrict__ cw, const int* __restrict__ rp,
                                             const float* __restrict__ bias, float* __restrict__ Hn, int n) {
    int wid  = (blockIdx.x * 256 + threadIdx.x) >> 6;
    int lane = threadIdx.x & 63;
    if (wid >= n) return;
    int s = rp[wid], e = rp[wid + 1];
    int f = lane * 2;
    float a0 = 0.f, a1 = 0.f;
    int i = s;
    for (; i + 4 <= e; i += 4) {
        int   s0 = cs[i], s1 = cs[i + 1], s2 = cs[i + 2], s3 = cs[i + 3];
        float w0 = cw[i], w1 = cw[i + 1], w2 = cw[i + 2], w3 = cw[i + 3];
        float2 v0 = *(const float2*)&XW[(size_t)s0 * 128 + f];
        float2 v1 = *(const float2*)&XW[(size_t)s1 * 128 + f];
        float2 v2 = *(const float2*)&XW[(size_t)s2 * 128 + f];
        float2 v3 = *(const float2*)&XW[(size_t)s3 * 128 + f];
        a0 += w0 * v0.x + w1 * v1.x + w2 * v2.x + w3 * v3.x;
        a1 += w0 * v0.y + w1 * v1.y + w2 * v2.y + w3 * v3.y;
    }
    for (; i < e; ++i) {
        int s0 = cs[i];
        float w = cw[i];
        float2 v = *(const float2*)&XW[(size_t)s0 * 128 + f];
        a0 += w * v.x;
        a1 += w * v.y;
    }
    a0 = fmaxf(a0 + bias[f],     0.f);
    a1 = fmaxf(a1 + bias[f + 1], 0.f);
    float2 r2; r2.x = a0; r2.y = a1;
    *(float2*)&Hn[(size_t)wid * 128 + f] = r2;
}

// ---------------- pooling ----------------

__global__ __launch_bounds__(256) void k_bounds(const int* __restrict__ batch, int* __restrict__ startg,
                                                int n, int g) {
    int i = blockIdx.x * 256 + threadIdx.x;
    if (i >= n) return;
    int b = batch[i];
    if (i == 0) {
        for (int q = 0; q <= b; ++q) startg[q] = 0;
    } else {
        int pb = batch[i - 1];
        for (int q = pb + 1; q <= b; ++q) startg[q] = i;
    }
    if (i == n - 1) {
        for (int q = b + 1; q <= g; ++q) startg[q] = n;
    }
}

// one block (128 threads) per graph: sum / mean / max over its contiguous node range
__global__ __launch_bounds__(128) void k_pool(const float* __restrict__ H, const int* __restrict__ startg,
                                              float* __restrict__ P) {
    int g = blockIdx.x;
    int f = threadIdx.x;
    int s = startg[g], e = startg[g + 1];
    float sum = 0.f, mx = 0.f;  // h >= 0 after relu; 0-init reproduces the isfinite guard
    for (int nidx = s; nidx < e; ++nidx) {
        float v = H[(size_t)nidx * 128 + f];
        sum += v;
        mx = fmaxf(mx, v);
    }
    float cnt = (float)(e - s);
    P[(size_t)g * 384 + f]       = sum;
    P[(size_t)g * 384 + 128 + f] = sum / fmaxf(cnt, 1.f);
    P[(size_t)g * 384 + 256 + f] = mx;
}

// ---------------- head: lin1 + relu + lin2 + log_softmax ----------------
__global__ __launch_bounds__(128) void k_head(const float* __restrict__ P,
                                              const float* __restrict__ w1, const float* __restrict__ b1,
                                              const float* __restrict__ w2, const float* __restrict__ b2,
                                              float* __restrict__ out) {
    __shared__ float gv[384];
    __shared__ float o1[128];
    int g = blockIdx.x, t = threadIdx.x;
    gv[t]       = P[(size_t)g * 384 + t];
    gv[t + 128] = P[(size_t)g * 384 + 128 + t];
    gv[t + 256] = P[(size_t)g * 384 + 256 + t];
    __syncthreads();
    float acc = b1[t];
#pragma unroll 8
    for (int k = 0; k < 384; ++k) acc = fmaf(gv[k], w1[k * 128 + t], acc);
    o1[t] = fmaxf(acc, 0.f);
    __syncthreads();
    if (t < 64) {
        float p0 = o1[t] * w2[t * 2 + 0] + o1[t + 64] * w2[(t + 64) * 2 + 0];
        float p1 = o1[t] * w2[t * 2 + 1] + o1[t + 64] * w2[(t + 64) * 2 + 1];
        for (int off = 32; off > 0; off >>= 1) {
            p0 += __shfl_down(p0, off);
            p1 += __shfl_down(p1, off);
        }
        if (t == 0) {
            float l0 = p0 + b2[0], l1 = p1 + b2[1];
            float m = fmaxf(l0, l1);
            float lse = m + logf(expf(l0 - m) + expf(l1 - m));
            out[g * 2 + 0] = l0 - lse;
            out[g * 2 + 1] = l1 - lse;
        }
    }
}

// ---------------- launcher ----------------

extern "C" void kernel_launch(void* const* d_in, const int* in_sizes, int n_in,
                              void* d_out, int out_size, void* d_ws, size_t ws_size,
                              hipStream_t stream) {
    const float* x     = (const float*)d_in[0];
    const int*   ei    = (const int*)d_in[1];
    const int*   batch = (const int*)d_in[2];
    const float* W0    = (const float*)d_in[3];
    const float* b0    = (const float*)d_in[4];
    const float* Wh    = (const float*)d_in[5];
    const float* bh    = (const float*)d_in[6];
    const float* l1w   = (const float*)d_in[7];
    const float* l1b   = (const float*)d_in[8];
    const float* l2w   = (const float*)d_in[9];
    const float* l2b   = (const float*)d_in[10];
    float* out = (float*)d_out;

    const int N  = in_sizes[0] / 128;
    const int E  = in_sizes[1] / 2;
    const int G  = out_size / 2;
    const int LX = in_sizes[5] / (128 * 128);

    const int* src = ei;
    const int* dst = ei + E;

    char* p = (char*)d_ws;
    auto alloc = [&](size_t bytes) -> void* {
        void* r = (void*)p;
        p += (bytes + 255) & ~(size_t)255;
        return r;
    };
    int*   ideg   = (int*)alloc((size_t)N * 4);
    int*   rowptr = (int*)alloc((size_t)(N + 1) * 4);
    int*   cursor = (int*)alloc((size_t)N * 4);
    float* dinv   = (float*)alloc((size_t)N * 4);
    int*   bsum   = (int*)alloc(1024);
    int*   bbase  = (int*)alloc(1024);
    int*   startg = (int*)alloc((size_t)(G + 1) * 4);
    int*   csr_s  = (int*)alloc((size_t)(E + N) * 4);
    float* csr_w  = (float*)alloc((size_t)(E + N) * 4);
    float* hbuf   = (float*)alloc((size_t)N * 128 * 4);
    float* xwbuf  = (float*)alloc((size_t)N * 128 * 4);
    float* pooled = (float*)alloc((size_t)G * 384 * 4);

    const int nbN  = (N + 255) / 256;        // blocks over N
    const int nbE  = (E + 255) / 256;
    const int nbEN = (E + N + 255) / 256;

    // --- CSR setup (once per launch, reused by all layers) ---
    k_init_deg<<<nbN, 256, 0, stream>>>(ideg, N);
    k_count<<<nbE, 256, 0, stream>>>(dst, ideg, E);
    k_dinv<<<nbN, 256, 0, stream>>>(ideg, dinv, N);
    k_scan_a<<<nbN, 256, 0, stream>>>(ideg, rowptr, bsum, N);
    k_scan_b<<<1, 256, 0, stream>>>(bsum, bbase, nbN, rowptr, N);
    k_scan_c<<<nbN, 256, 0, stream>>>(rowptr, bbase, cursor, N);
    k_fill<<<nbEN, 256, 0, stream>>>(src, dst, dinv, cursor, csr_s, csr_w, E, N);

    // --- 4 GCN layers ---
    const int gemmBlocks = (N + 63) / 64;
    const int aggBlocks  = (N + 3) / 4;  // 4 waves per 256-thread block

    k_gemm<<<gemmBlocks, 256, 0, stream>>>(x, W0, xwbuf, N);
    k_agg<<<aggBlocks, 256, 0, stream>>>(xwbuf, csr_s, csr_w, rowptr, b0, hbuf, N);
    for (int l = 0; l < LX; ++l) {
        k_gemm<<<gemmBlocks, 256, 0, stream>>>(hbuf, Wh + (size_t)l * 128 * 128, xwbuf, N);
        k_agg<<<aggBlocks, 256, 0, stream>>>(xwbuf, csr_s, csr_w, rowptr, bh + (size_t)l * 128, hbuf, N);
    }

    // --- pooling + head ---
    k_bounds<<<nbN, 256, 0, stream>>>(batch, startg, N, G);
    k_pool<<<G, 128, 0, stream>>>(hbuf, startg, pooled);
    k_head<<<G, 128, 0, stream>>>(pooled, l1w, l1b, l2w, l2b, out);
}

// Round 3
// 507.711 us; speedup vs baseline: 1.2169x; 1.2169x over previous
//
#include <hip/hip_runtime.h>
#include <hip/hip_fp16.h>
#include <cstddef>

typedef __attribute__((ext_vector_type(8))) unsigned short ushort8;

// ---------------- setup kernels ----------------

__global__ __launch_bounds__(256) void k_init_deg(int* __restrict__ ideg, int n) {
    int i = blockIdx.x * 256 + threadIdx.x;
    if (i < n) ideg[i] = 1;  // self-loop
}

__global__ __launch_bounds__(256) void k_count(const int* __restrict__ dst, int* __restrict__ ideg, int e) {
    int i = blockIdx.x * 256 + threadIdx.x;
    if (i < e) atomicAdd(&ideg[dst[i]], 1);
}

__global__ __launch_bounds__(256) void k_dinv(const int* __restrict__ ideg, float* __restrict__ dinv, int n) {
    int i = blockIdx.x * 256 + threadIdx.x;
    if (i < n) dinv[i] = rsqrtf((float)ideg[i]);
}

// block-wise inclusive scan (256/block), writes block-local exclusive into rowptr, block sums to bsum
__global__ __launch_bounds__(256) void k_scan_a(const int* __restrict__ cnt, int* __restrict__ rowptr,
                                                int* __restrict__ bsum, int n) {
    __shared__ int sh[256];
    int t = threadIdx.x;
    int i = blockIdx.x * 256 + t;
    int v = (i < n) ? cnt[i] : 0;
    sh[t] = v;
    __syncthreads();
    for (int off = 1; off < 256; off <<= 1) {
        int x = (t >= off) ? sh[t - off] : 0;
        __syncthreads();
        sh[t] += x;
        __syncthreads();
    }
    if (i < n) rowptr[i] = sh[t] - v;          // block-local exclusive
    if (t == 255) bsum[blockIdx.x] = sh[255];  // block total
}

// single-block scan of block sums -> bbase (exclusive); writes rowptr[n] = grand total
__global__ __launch_bounds__(256) void k_scan_b(const int* __restrict__ bsum, int* __restrict__ bbase,
                                                int nb, int* __restrict__ rowptr, int n) {
    __shared__ int sh[256];
    int t = threadIdx.x;
    int v = (t < nb) ? bsum[t] : 0;
    sh[t] = v;
    __syncthreads();
    for (int off = 1; off < 256; off <<= 1) {
        int x = (t >= off) ? sh[t - off] : 0;
        __syncthreads();
        sh[t] += x;
        __syncthreads();
    }
    if (t < nb) bbase[t] = sh[t] - v;
    if (t == 255) rowptr[n] = sh[255];
}

__global__ __launch_bounds__(256) void k_scan_c(int* __restrict__ rowptr, const int* __restrict__ bbase,
                                                int* __restrict__ cursor, int n) {
    int i = blockIdx.x * 256 + threadIdx.x;
    if (i < n) {
        int r = rowptr[i] + bbase[i >> 8];
        rowptr[i] = r;
        cursor[i] = r;
    }
}

// scatter edges (and self-loops) into CSR sorted by dst; only src index is stored
// (edge weight dinv[s]*dinv[d] is folded into the data: GEMM pre-scales rows by
//  dinv[src], aggregation post-scales by dinv[dst])
__global__ __launch_bounds__(256) void k_fill(const int* __restrict__ src, const int* __restrict__ dst,
                                              int* __restrict__ cursor, int* __restrict__ csr_s,
                                              int e, int n) {
    int i = blockIdx.x * 256 + threadIdx.x;
    if (i >= e + n) return;
    int s, d;
    if (i < e) { s = src[i]; d = dst[i]; }
    else       { s = i - e; d = s; }
    int pos = atomicAdd(&cursor[d], 1);
    csr_s[pos] = s;
}

// ---------------- dense GEMM: O[r,:] = dinv[r] * (H[r,:] @ W)  as fp16 ----------------
// block = 256 threads, tile = 64 rows x 128 cols, per-thread 4x8
__global__ __launch_bounds__(256) void k_gemm(const float* __restrict__ H, const float* __restrict__ W,
                                              const float* __restrict__ dinv, __half* __restrict__ O,
                                              int nrows) {
    __shared__ float Wl[128 * 128];
    __shared__ float Hl[64][132];
    const int t = threadIdx.x;
    const int row0 = blockIdx.x * 64;

#pragma unroll
    for (int i = 0; i < 16; ++i) {
        int idx = (t + i * 256) * 4;
        *(float4*)&Wl[idx] = *(const float4*)&W[idx];
    }
#pragma unroll
    for (int i = 0; i < 8; ++i) {
        int idx = t + i * 256;       // float4 index within 64x128 tile
        int r = idx >> 5;            // /32 float4s per row
        int c = (idx & 31) << 2;
        float4 v;
        if (row0 + r < nrows) v = *(const float4*)&H[(size_t)(row0 + r) * 128 + c];
        else                  v = make_float4(0.f, 0.f, 0.f, 0.f);
        *(float4*)&Hl[r][c] = v;
    }
    __syncthreads();

    const int ct = t & 15, rt = t >> 4;
    const int c0 = ct * 8, r0 = rt * 4;
    float acc[4][8];
#pragma unroll
    for (int i = 0; i < 4; ++i)
#pragma unroll
        for (int j = 0; j < 8; ++j) acc[i][j] = 0.f;

#pragma unroll 4
    for (int k = 0; k < 128; ++k) {
        float4 w0 = *(float4*)&Wl[k * 128 + c0];
        float4 w1 = *(float4*)&Wl[k * 128 + c0 + 4];
        float wv[8] = {w0.x, w0.y, w0.z, w0.w, w1.x, w1.y, w1.z, w1.w};
        float hv[4] = {Hl[r0 + 0][k], Hl[r0 + 1][k], Hl[r0 + 2][k], Hl[r0 + 3][k]};
#pragma unroll
        for (int i = 0; i < 4; ++i)
#pragma unroll
            for (int j = 0; j < 8; ++j) acc[i][j] = fmaf(hv[i], wv[j], acc[i][j]);
    }

#pragma unroll
    for (int i = 0; i < 4; ++i) {
        int r = row0 + r0 + i;
        if (r < nrows) {
            float dv = dinv[r];
            ushort8 pk;
#pragma unroll
            for (int j = 0; j < 8; ++j)
                pk[j] = __half_as_ushort(__float2half(acc[i][j] * dv));
            *(ushort8*)&O[(size_t)r * 128 + c0] = pk;
        }
    }
}

// ---------------- aggregation: Hn[v] = relu(dinv[v]*sum_e XWs[src[e]] + bias), CSR by dst ----------------
// one 64-lane wave per node, lane handles features (2*lane, 2*lane+1); XWs rows are fp16, pre-scaled
__global__ __launch_bounds__(256) void k_agg(const __half* __restrict__ XW, const int* __restrict__ cs,
                                             const int* __restrict__ rp, const float* __restrict__ dinv,
                                             const float* __restrict__ bias, float* __restrict__ Hn, int n) {
    int wid  = (blockIdx.x * 256 + threadIdx.x) >> 6;
    int lane = threadIdx.x & 63;
    if (wid >= n) return;
    int s = rp[wid], e = rp[wid + 1];
    const __half2* X2 = (const __half2*)XW;
    float a0 = 0.f, a1 = 0.f;
    int i = s;
    for (; i + 4 <= e; i += 4) {
        int s0 = cs[i], s1 = cs[i + 1], s2 = cs[i + 2], s3 = cs[i + 3];
        float2 v0 = __half22float2(X2[(size_t)s0 * 64 + lane]);
        float2 v1 = __half22float2(X2[(size_t)s1 * 64 + lane]);
        float2 v2 = __half22float2(X2[(size_t)s2 * 64 + lane]);
        float2 v3 = __half22float2(X2[(size_t)s3 * 64 + lane]);
        a0 += v0.x + v1.x + v2.x + v3.x;
        a1 += v0.y + v1.y + v2.y + v3.y;
    }
    for (; i < e; ++i) {
        float2 v = __half22float2(X2[(size_t)cs[i] * 64 + lane]);
        a0 += v.x;
        a1 += v.y;
    }
    float dv = dinv[wid];
    int f = lane * 2;
    a0 = fmaxf(fmaf(a0, dv, bias[f]),     0.f);
    a1 = fmaxf(fmaf(a1, dv, bias[f + 1]), 0.f);
    float2 r2; r2.x = a0; r2.y = a1;
    *(float2*)&Hn[(size_t)wid * 128 + f] = r2;
}

// ---------------- pooling ----------------

__global__ __launch_bounds__(256) void k_bounds(const int* __restrict__ batch, int* __restrict__ startg,
                                                int n, int g) {
    int i = blockIdx.x * 256 + threadIdx.x;
    if (i >= n) return;
    int b = batch[i];
    if (i == 0) {
        for (int q = 0; q <= b; ++q) startg[q] = 0;
    } else {
        int pb = batch[i - 1];
        for (int q = pb + 1; q <= b; ++q) startg[q] = i;
    }
    if (i == n - 1) {
        for (int q = b + 1; q <= g; ++q) startg[q] = n;
    }
}

// one block (256 threads = 2 halves) per graph: sum / mean / max over its contiguous node range
__global__ __launch_bounds__(256) void k_pool(const float* __restrict__ H, const int* __restrict__ startg,
                                              float* __restrict__ P) {
    __shared__ float ss[256], sm[256];
    int g = blockIdx.x;
    int t = threadIdx.x;
    int f = t & 127, h = t >> 7;
    int s = startg[g], e = startg[g + 1];
    float sum = 0.f, mx = 0.f;  // h >= 0 after relu; 0-init reproduces the isfinite guard
    for (int nidx = s + h; nidx < e; nidx += 2) {
        float v = H[(size_t)nidx * 128 + f];
        sum += v;
        mx = fmaxf(mx, v);
    }
    ss[t] = sum;
    sm[t] = mx;
    __syncthreads();
    if (t < 128) {
        sum = ss[t] + ss[t + 128];
        mx = fmaxf(sm[t], sm[t + 128]);
        float cnt = (float)(e - s);
        P[(size_t)g * 384 + f]       = sum;
        P[(size_t)g * 384 + 128 + f] = sum / fmaxf(cnt, 1.f);
        P[(size_t)g * 384 + 256 + f] = mx;
    }
}

// ---------------- head: lin1 + relu + lin2 + log_softmax ----------------
__global__ __launch_bounds__(128) void k_head(const float* __restrict__ P,
                                              const float* __restrict__ w1, const float* __restrict__ b1,
                                              const float* __restrict__ w2, const float* __restrict__ b2,
                                              float* __restrict__ out) {
    __shared__ float gv[384];
    __shared__ float o1[128];
    int g = blockIdx.x, t = threadIdx.x;
    gv[t]       = P[(size_t)g * 384 + t];
    gv[t + 128] = P[(size_t)g * 384 + 128 + t];
    gv[t + 256] = P[(size_t)g * 384 + 256 + t];
    __syncthreads();
    float acc = b1[t];
#pragma unroll 8
    for (int k = 0; k < 384; ++k) acc = fmaf(gv[k], w1[k * 128 + t], acc);
    o1[t] = fmaxf(acc, 0.f);
    __syncthreads();
    if (t < 64) {
        float p0 = o1[t] * w2[t * 2 + 0] + o1[t + 64] * w2[(t + 64) * 2 + 0];
        float p1 = o1[t] * w2[t * 2 + 1] + o1[t + 64] * w2[(t + 64) * 2 + 1];
        for (int off = 32; off > 0; off >>= 1) {
            p0 += __shfl_down(p0, off);
            p1 += __shfl_down(p1, off);
        }
        if (t == 0) {
            float l0 = p0 + b2[0], l1 = p1 + b2[1];
            float m = fmaxf(l0, l1);
            float lse = m + logf(expf(l0 - m) + expf(l1 - m));
            out[g * 2 + 0] = l0 - lse;
            out[g * 2 + 1] = l1 - lse;
        }
    }
}

// ---------------- launcher ----------------

extern "C" void kernel_launch(void* const* d_in, const int* in_sizes, int n_in,
                              void* d_out, int out_size, void* d_ws, size_t ws_size,
                              hipStream_t stream) {
    const float* x     = (const float*)d_in[0];
    const int*   ei    = (const int*)d_in[1];
    const int*   batch = (const int*)d_in[2];
    const float* W0    = (const float*)d_in[3];
    const float* b0    = (const float*)d_in[4];
    const float* Wh    = (const float*)d_in[5];
    const float* bh    = (const float*)d_in[6];
    const float* l1w   = (const float*)d_in[7];
    const float* l1b   = (const float*)d_in[8];
    const float* l2w   = (const float*)d_in[9];
    const float* l2b   = (const float*)d_in[10];
    float* out = (float*)d_out;

    const int N  = in_sizes[0] / 128;
    const int E  = in_sizes[1] / 2;
    const int G  = out_size / 2;
    const int LX = in_sizes[5] / (128 * 128);

    const int* src = ei;
    const int* dst = ei + E;

    char* p = (char*)d_ws;
    auto alloc = [&](size_t bytes) -> void* {
        void* r = (void*)p;
        p += (bytes + 255) & ~(size_t)255;
        return r;
    };
    int*    ideg   = (int*)alloc((size_t)N * 4);
    int*    rowptr = (int*)alloc((size_t)(N + 1) * 4);
    int*    cursor = (int*)alloc((size_t)N * 4);
    float*  dinv   = (float*)alloc((size_t)N * 4);
    int*    bsum   = (int*)alloc(1024);
    int*    bbase  = (int*)alloc(1024);
    int*    startg = (int*)alloc((size_t)(G + 1) * 4);
    int*    csr_s  = (int*)alloc((size_t)(E + N) * 4);
    float*  hbuf   = (float*)alloc((size_t)N * 128 * 4);
    __half* xwbuf  = (__half*)alloc((size_t)N * 128 * 2);
    float*  pooled = (float*)alloc((size_t)G * 384 * 4);

    const int nbN  = (N + 255) / 256;        // blocks over N
    const int nbE  = (E + 255) / 256;
    const int nbEN = (E + N + 255) / 256;

    // --- CSR setup (once per launch, reused by all layers) ---
    k_init_deg<<<nbN, 256, 0, stream>>>(ideg, N);
    k_count<<<nbE, 256, 0, stream>>>(dst, ideg, E);
    k_dinv<<<nbN, 256, 0, stream>>>(ideg, dinv, N);
    k_scan_a<<<nbN, 256, 0, stream>>>(ideg, rowptr, bsum, N);
    k_scan_b<<<1, 256, 0, stream>>>(bsum, bbase, nbN, rowptr, N);
    k_scan_c<<<nbN, 256, 0, stream>>>(rowptr, bbase, cursor, N);
    k_fill<<<nbEN, 256, 0, stream>>>(src, dst, cursor, csr_s, E, N);

    // --- 4 GCN layers ---
    const int gemmBlocks = (N + 63) / 64;
    const int aggBlocks  = (N + 3) / 4;  // 4 waves per 256-thread block

    k_gemm<<<gemmBlocks, 256, 0, stream>>>(x, W0, dinv, xwbuf, N);
    k_agg<<<aggBlocks, 256, 0, stream>>>(xwbuf, csr_s, rowptr, dinv, b0, hbuf, N);
    for (int l = 0; l < LX; ++l) {
        k_gemm<<<gemmBlocks, 256, 0, stream>>>(hbuf, Wh + (size_t)l * 128 * 128, dinv, xwbuf, N);
        k_agg<<<aggBlocks, 256, 0, stream>>>(xwbuf, csr_s, rowptr, dinv, bh + (size_t)l * 128, hbuf, N);
    }

    // --- pooling + head ---
    k_bounds<<<nbN, 256, 0, stream>>>(batch, startg, N, G);
    k_pool<<<G, 256, 0, stream>>>(hbuf, startg, pooled);
    k_head<<<G, 128, 0, stream>>>(pooled, l1w, l1b, l2w, l2b, out);
}

// Round 4
// 354.573 us; speedup vs baseline: 1.7425x; 1.4319x over previous
//
#include <hip/hip_runtime.h>
#include <hip/hip_fp16.h>
#include <cstddef>

typedef _Float16 f16x8 __attribute__((ext_vector_type(8)));
typedef float f32x4 __attribute__((ext_vector_type(4)));
typedef unsigned short ushort8 __attribute__((ext_vector_type(8)));

// ---------------- setup kernels ----------------

__global__ __launch_bounds__(256) void k_init_deg(int* __restrict__ ideg, int n) {
    int i = blockIdx.x * 256 + threadIdx.x;
    if (i < n) ideg[i] = 1;  // self-loop
}

__global__ __launch_bounds__(256) void k_count(const int* __restrict__ dst, int* __restrict__ ideg, int e) {
    int i0 = (blockIdx.x * 256 + threadIdx.x) * 4;
    if (i0 >= e) return;
    if (i0 + 4 <= e) {
        int4 dv = *(const int4*)&dst[i0];
        atomicAdd(&ideg[dv.x], 1);
        atomicAdd(&ideg[dv.y], 1);
        atomicAdd(&ideg[dv.z], 1);
        atomicAdd(&ideg[dv.w], 1);
    } else {
        for (int i = i0; i < e; ++i) atomicAdd(&ideg[dst[i]], 1);
    }
}

__global__ __launch_bounds__(256) void k_dinv(const int* __restrict__ ideg, float* __restrict__ dinv, int n) {
    int i = blockIdx.x * 256 + threadIdx.x;
    if (i < n) dinv[i] = rsqrtf((float)ideg[i]);
}

// block-wise inclusive scan (256/block), writes block-local exclusive into rowptr, block sums to bsum
__global__ __launch_bounds__(256) void k_scan_a(const int* __restrict__ cnt, int* __restrict__ rowptr,
                                                int* __restrict__ bsum, int n) {
    __shared__ int sh[256];
    int t = threadIdx.x;
    int i = blockIdx.x * 256 + t;
    int v = (i < n) ? cnt[i] : 0;
    sh[t] = v;
    __syncthreads();
    for (int off = 1; off < 256; off <<= 1) {
        int x = (t >= off) ? sh[t - off] : 0;
        __syncthreads();
        sh[t] += x;
        __syncthreads();
    }
    if (i < n) rowptr[i] = sh[t] - v;          // block-local exclusive
    if (t == 255) bsum[blockIdx.x] = sh[255];  // block total
}

__global__ __launch_bounds__(256) void k_scan_b(const int* __restrict__ bsum, int* __restrict__ bbase,
                                                int nb, int* __restrict__ rowptr, int n) {
    __shared__ int sh[256];
    int t = threadIdx.x;
    int v = (t < nb) ? bsum[t] : 0;
    sh[t] = v;
    __syncthreads();
    for (int off = 1; off < 256; off <<= 1) {
        int x = (t >= off) ? sh[t - off] : 0;
        __syncthreads();
        sh[t] += x;
        __syncthreads();
    }
    if (t < nb) bbase[t] = sh[t] - v;
    if (t == 255) rowptr[n] = sh[255];
}

__global__ __launch_bounds__(256) void k_scan_c(int* __restrict__ rowptr, const int* __restrict__ bbase,
                                                int* __restrict__ cursor, int n) {
    int i = blockIdx.x * 256 + threadIdx.x;
    if (i < n) {
        int r = rowptr[i] + bbase[i >> 8];
        rowptr[i] = r;
        cursor[i] = r;
    }
}

// scatter edges (and self-loops) into CSR sorted by dst; 4 edges per thread for MLP
__global__ __launch_bounds__(256) void k_fill(const int* __restrict__ src, const int* __restrict__ dst,
                                              int* __restrict__ cursor, int* __restrict__ csr_s,
                                              int e, int n) {
    int i0 = (blockIdx.x * 256 + threadIdx.x) * 4;
    int tot = e + n;
    if (i0 >= tot) return;
    int s[4], d[4];
    int cnt = min(4, tot - i0);
    if (i0 + 4 <= e && ((e & 3) == 0 || i0 + 4 <= (e & ~3))) {
        int4 sv = *(const int4*)&src[i0];
        int4 dv = *(const int4*)&dst[i0];
        s[0] = sv.x; s[1] = sv.y; s[2] = sv.z; s[3] = sv.w;
        d[0] = dv.x; d[1] = dv.y; d[2] = dv.z; d[3] = dv.w;
    } else {
        for (int j = 0; j < cnt; ++j) {
            int i = i0 + j;
            if (i < e) { s[j] = src[i]; d[j] = dst[i]; }
            else       { s[j] = i - e; d[j] = s[j]; }
        }
    }
#pragma unroll
    for (int j = 0; j < 4; ++j) {
        if (j < cnt) {
            int pos = atomicAdd(&cursor[d[j]], 1);
            csr_s[pos] = s[j];
        }
    }
}

// ---------------- fp32 -> fp16 conversion (8 elems/thread) ----------------
__global__ __launch_bounds__(256) void k_cvt(const float* __restrict__ X, __half* __restrict__ Y, int n8) {
    int i = blockIdx.x * 256 + threadIdx.x;
    if (i >= n8) return;
    float4 v0 = *(const float4*)&X[(size_t)i * 8];
    float4 v1 = *(const float4*)&X[(size_t)i * 8 + 4];
    ushort8 o;
    o[0] = __half_as_ushort(__float2half(v0.x));
    o[1] = __half_as_ushort(__float2half(v0.y));
    o[2] = __half_as_ushort(__float2half(v0.z));
    o[3] = __half_as_ushort(__float2half(v0.w));
    o[4] = __half_as_ushort(__float2half(v1.x));
    o[5] = __half_as_ushort(__float2half(v1.y));
    o[6] = __half_as_ushort(__float2half(v1.z));
    o[7] = __half_as_ushort(__float2half(v1.w));
    *(ushort8*)&Y[(size_t)i * 8] = o;
}

// ---------------- W -> fragment-ordered fp16 pack ----------------
// B-fragment layout for mfma_f32_16x16x32_f16: lane l, elem i -> B[k][col],
//   k = kc*32 + (l>>4)*8 + i, col = nt*16 + (l&15)
// flat index o = ((nt*4+kc)*64 + l)*8 + i  -> lane-contiguous 16B chunks
__global__ __launch_bounds__(256) void k_wprep(const float* __restrict__ W0, const float* __restrict__ Wh,
                                               __half* __restrict__ WP) {
    int layer = blockIdx.x;
    const float* W = (layer == 0) ? W0 : Wh + (size_t)(layer - 1) * 16384;
    __half* out = WP + (size_t)layer * 16384;
    int t = threadIdx.x;
    for (int u = 0; u < 64; ++u) {
        int o = u * 256 + t;
        int i  = o & 7;
        int l  = (o >> 3) & 63;
        int kc = (o >> 9) & 3;
        int nt = o >> 11;
        int k   = kc * 32 + ((l >> 4) << 3) + i;
        int col = nt * 16 + (l & 15);
        out[o] = __float2half(W[k * 128 + col]);
    }
}

// ---------------- MFMA GEMM: O[r,:] = fp16( dinv[r] * (H[r,:] @ W) ) ----------------
// 256 threads = 4 waves; block tile 128 rows x 128 cols; wave = 32 rows.
// A (16x32 per tile) from global: lane l reads rows (l&15), k = kc*32 + (l>>4)*8 .. +7
// B from LDS fragment-packed W'; C/D: col=l&15, row=(l>>4)*4+reg  [m89-verified]
__global__ __launch_bounds__(256) void k_gemm(const __half* __restrict__ H, const __half* __restrict__ WP,
                                              const float* __restrict__ dinv, __half* __restrict__ O,
                                              int n) {
    __shared__ __half wl[16384];
    const int t = threadIdx.x;
#pragma unroll
    for (int u = 0; u < 8; ++u) {
        int idx = (u * 256 + t) * 8;
        *(ushort8*)&wl[idx] = *(const ushort8*)&WP[idx];
    }
    const int wid = t >> 6, l = t & 63;
    const int row0 = blockIdx.x * 128 + wid * 32;
    const int ar = l & 15, g = l >> 4;

    f16x8 a[2][4];
    float dv[2][4];
#pragma unroll
    for (int mt = 0; mt < 2; ++mt) {
        int row = row0 + mt * 16 + ar;
        int rc = min(row, n - 1);
#pragma unroll
        for (int kc = 0; kc < 4; ++kc)
            a[mt][kc] = *(const f16x8*)&H[(size_t)rc * 128 + kc * 32 + g * 8];
#pragma unroll
        for (int r = 0; r < 4; ++r) {
            int orow = row0 + mt * 16 + g * 4 + r;
            dv[mt][r] = dinv[min(orow, n - 1)];
        }
    }
    __syncthreads();

#pragma unroll
    for (int nt = 0; nt < 8; ++nt) {
        f16x8 b[4];
#pragma unroll
        for (int kc = 0; kc < 4; ++kc)
            b[kc] = *(f16x8*)&wl[((nt * 4 + kc) * 64 + l) * 8];
#pragma unroll
        for (int mt = 0; mt < 2; ++mt) {
            f32x4 acc = {0.f, 0.f, 0.f, 0.f};
#pragma unroll
            for (int kc = 0; kc < 4; ++kc)
                acc = __builtin_amdgcn_mfma_f32_16x16x32_f16(a[mt][kc], b[kc], acc, 0, 0, 0);
#pragma unroll
            for (int r = 0; r < 4; ++r) {
                int orow = row0 + mt * 16 + g * 4 + r;
                if (orow < n)
                    O[(size_t)orow * 128 + nt * 16 + ar] = __float2half(acc[r] * dv[mt][r]);
            }
        }
    }
}

// ---------------- aggregation: h[v] = relu(dinv[v]*sum XW[src] + bias) -> fp16 ----------------
__global__ __launch_bounds__(256) void k_agg(const __half* __restrict__ XW, const int* __restrict__ cs,
                                             const int* __restrict__ rp, const float* __restrict__ dinv,
                                             const float* __restrict__ bias, __half* __restrict__ Hn, int n) {
    int wid  = (blockIdx.x * 256 + threadIdx.x) >> 6;
    int lane = threadIdx.x & 63;
    if (wid >= n) return;
    int s = rp[wid], e = rp[wid + 1];
    const __half2* X2 = (const __half2*)XW;
    float a0 = 0.f, a1 = 0.f;
    int i = s;
    for (; i + 8 <= e; i += 8) {
        int idx[8];
#pragma unroll
        for (int j = 0; j < 8; ++j) idx[j] = cs[i + j];
        float2 v[8];
#pragma unroll
        for (int j = 0; j < 8; ++j) v[j] = __half22float2(X2[(size_t)idx[j] * 64 + lane]);
#pragma unroll
        for (int j = 0; j < 8; ++j) { a0 += v[j].x; a1 += v[j].y; }
    }
    for (; i + 4 <= e; i += 4) {
        int s0 = cs[i], s1 = cs[i + 1], s2 = cs[i + 2], s3 = cs[i + 3];
        float2 v0 = __half22float2(X2[(size_t)s0 * 64 + lane]);
        float2 v1 = __half22float2(X2[(size_t)s1 * 64 + lane]);
        float2 v2 = __half22float2(X2[(size_t)s2 * 64 + lane]);
        float2 v3 = __half22float2(X2[(size_t)s3 * 64 + lane]);
        a0 += v0.x + v1.x + v2.x + v3.x;
        a1 += v0.y + v1.y + v2.y + v3.y;
    }
    for (; i < e; ++i) {
        float2 v = __half22float2(X2[(size_t)cs[i] * 64 + lane]);
        a0 += v.x;
        a1 += v.y;
    }
    float dvv = dinv[wid];
    int f = lane * 2;
    a0 = fmaxf(fmaf(a0, dvv, bias[f]),     0.f);
    a1 = fmaxf(fmaf(a1, dvv, bias[f + 1]), 0.f);
    ((__half2*)Hn)[(size_t)wid * 64 + lane] = __floats2half2_rn(a0, a1);
}

// ---------------- pooling ----------------

__global__ __launch_bounds__(256) void k_bounds(const int* __restrict__ batch, int* __restrict__ startg,
                                                int n, int g) {
    int i = blockIdx.x * 256 + threadIdx.x;
    if (i >= n) return;
    int b = batch[i];
    if (i == 0) {
        for (int q = 0; q <= b; ++q) startg[q] = 0;
    } else {
        int pb = batch[i - 1];
        for (int q = pb + 1; q <= b; ++q) startg[q] = i;
    }
    if (i == n - 1) {
        for (int q = b + 1; q <= g; ++q) startg[q] = n;
    }
}

// one block (256 threads = 2 halves) per graph: sum / mean / max over contiguous node range (fp16 H)
__global__ __launch_bounds__(256) void k_pool(const __half* __restrict__ H, const int* __restrict__ startg,
                                              float* __restrict__ P) {
    __shared__ float ss[256], sm[256];
    int g = blockIdx.x;
    int t = threadIdx.x;
    int f = t & 127, h = t >> 7;
    int s = startg[g], e = startg[g + 1];
    float sum = 0.f, mx = 0.f;  // h >= 0 after relu; 0-init reproduces the isfinite guard
    for (int nidx = s + h; nidx < e; nidx += 2) {
        float v = __half2float(H[(size_t)nidx * 128 + f]);
        sum += v;
        mx = fmaxf(mx, v);
    }
    ss[t] = sum;
    sm[t] = mx;
    __syncthreads();
    if (t < 128) {
        sum = ss[t] + ss[t + 128];
        mx = fmaxf(sm[t], sm[t + 128]);
        float cnt = (float)(e - s);
        P[(size_t)g * 384 + f]       = sum;
        P[(size_t)g * 384 + 128 + f] = sum / fmaxf(cnt, 1.f);
        P[(size_t)g * 384 + 256 + f] = mx;
    }
}

// ---------------- head: lin1 + relu + lin2 + log_softmax ----------------
__global__ __launch_bounds__(128) void k_head(const float* __restrict__ P,
                                              const float* __restrict__ w1, const float* __restrict__ b1,
                                              const float* __restrict__ w2, const float* __restrict__ b2,
                                              float* __restrict__ out) {
    __shared__ float gv[384];
    __shared__ float o1[128];
    int g = blockIdx.x, t = threadIdx.x;
    gv[t]       = P[(size_t)g * 384 + t];
    gv[t + 128] = P[(size_t)g * 384 + 128 + t];
    gv[t + 256] = P[(size_t)g * 384 + 256 + t];
    __syncthreads();
    float acc = b1[t];
#pragma unroll 8
    for (int k = 0; k < 384; ++k) acc = fmaf(gv[k], w1[k * 128 + t], acc);
    o1[t] = fmaxf(acc, 0.f);
    __syncthreads();
    if (t < 64) {
        float p0 = o1[t] * w2[t * 2 + 0] + o1[t + 64] * w2[(t + 64) * 2 + 0];
        float p1 = o1[t] * w2[t * 2 + 1] + o1[t + 64] * w2[(t + 64) * 2 + 1];
        for (int off = 32; off > 0; off >>= 1) {
            p0 += __shfl_down(p0, off);
            p1 += __shfl_down(p1, off);
        }
        if (t == 0) {
            float l0 = p0 + b2[0], l1 = p1 + b2[1];
            float m = fmaxf(l0, l1);
            float lse = m + logf(expf(l0 - m) + expf(l1 - m));
            out[g * 2 + 0] = l0 - lse;
            out[g * 2 + 1] = l1 - lse;
        }
    }
}

// ---------------- launcher ----------------

extern "C" void kernel_launch(void* const* d_in, const int* in_sizes, int n_in,
                              void* d_out, int out_size, void* d_ws, size_t ws_size,
                              hipStream_t stream) {
    const float* x     = (const float*)d_in[0];
    const int*   ei    = (const int*)d_in[1];
    const int*   batch = (const int*)d_in[2];
    const float* W0    = (const float*)d_in[3];
    const float* b0    = (const float*)d_in[4];
    const float* Wh    = (const float*)d_in[5];
    const float* bh    = (const float*)d_in[6];
    const float* l1w   = (const float*)d_in[7];
    const float* l1b   = (const float*)d_in[8];
    const float* l2w   = (const float*)d_in[9];
    const float* l2b   = (const float*)d_in[10];
    float* out = (float*)d_out;

    const int N  = in_sizes[0] / 128;
    const int E  = in_sizes[1] / 2;
    const int G  = out_size / 2;
    const int LX = in_sizes[5] / (128 * 128);

    const int* src = ei;
    const int* dst = ei + E;

    char* p = (char*)d_ws;
    auto alloc = [&](size_t bytes) -> void* {
        void* r = (void*)p;
        p += (bytes + 255) & ~(size_t)255;
        return r;
    };
    int*    ideg   = (int*)alloc((size_t)N * 4);
    int*    rowptr = (int*)alloc((size_t)(N + 1) * 4);
    int*    cursor = (int*)alloc((size_t)N * 4);
    float*  dinv   = (float*)alloc((size_t)N * 4);
    int*    bsum   = (int*)alloc(1024);
    int*    bbase  = (int*)alloc(1024);
    int*    startg = (int*)alloc((size_t)(G + 1) * 4);
    int*    csr_s  = (int*)alloc((size_t)(E + N) * 4);
    __half* x16    = (__half*)alloc((size_t)N * 128 * 2);
    __half* h16    = (__half*)alloc((size_t)N * 128 * 2);
    __half* xw16   = (__half*)alloc((size_t)N * 128 * 2);
    __half* wp     = (__half*)alloc((size_t)(LX + 1) * 16384 * 2);
    float*  pooled = (float*)alloc((size_t)G * 384 * 4);

    const int nbN  = (N + 255) / 256;
    const int nbE4 = (E + 1023) / 1024;
    const int nbT4 = (E + N + 1023) / 1024;

    // --- weight pack + input conversion (independent of CSR) ---
    k_wprep<<<LX + 1, 256, 0, stream>>>(W0, Wh, wp);
    k_cvt<<<(N * 16 + 255) / 256, 256, 0, stream>>>(x, x16, N * 16);  // N*128/8 items

    // --- CSR setup (once per launch, reused by all layers) ---
    k_init_deg<<<nbN, 256, 0, stream>>>(ideg, N);
    k_count<<<nbE4, 256, 0, stream>>>(dst, ideg, E);
    k_dinv<<<nbN, 256, 0, stream>>>(ideg, dinv, N);
    k_scan_a<<<nbN, 256, 0, stream>>>(ideg, rowptr, bsum, N);
    k_scan_b<<<1, 256, 0, stream>>>(bsum, bbase, nbN, rowptr, N);
    k_scan_c<<<nbN, 256, 0, stream>>>(rowptr, bbase, cursor, N);
    k_fill<<<nbT4, 256, 0, stream>>>(src, dst, cursor, csr_s, E, N);

    // --- 4 GCN layers ---
    const int gemmBlocks = (N + 127) / 128;
    const int aggBlocks  = (N + 3) / 4;

    k_gemm<<<gemmBlocks, 256, 0, stream>>>(x16, wp, dinv, xw16, N);
    k_agg<<<aggBlocks, 256, 0, stream>>>(xw16, csr_s, rowptr, dinv, b0, h16, N);
    for (int l = 0; l < LX; ++l) {
        k_gemm<<<gemmBlocks, 256, 0, stream>>>(h16, wp + (size_t)(l + 1) * 16384, dinv, xw16, N);
        k_agg<<<aggBlocks, 256, 0, stream>>>(xw16, csr_s, rowptr, dinv, bh + (size_t)l * 128, h16, N);
    }

    // --- pooling + head ---
    k_bounds<<<nbN, 256, 0, stream>>>(batch, startg, N, G);
    k_pool<<<G, 256, 0, stream>>>(h16, startg, pooled);
    k_head<<<G, 128, 0, stream>>>(pooled, l1w, l1b, l2w, l2b, out);
}

// Round 5
// 280.674 us; speedup vs baseline: 2.2013x; 1.2633x over previous
//
#include <hip/hip_runtime.h>
#include <hip/hip_fp16.h>
#include <cstddef>

typedef _Float16 f16x8 __attribute__((ext_vector_type(8)));
typedef float f32x4 __attribute__((ext_vector_type(4)));
typedef unsigned short ushort8 __attribute__((ext_vector_type(8)));

// ================= bucketed CSR construction =================
// Buckets of 256 consecutive dst nodes (bucket = dst>>8). NB = ceil(N/256) <= 256.

__global__ __launch_bounds__(256) void k_zero256(int* __restrict__ a) {
    a[threadIdx.x] = 0;
}

// per-block LDS histogram of dst>>8, flushed with 256 global atomics per block
__global__ __launch_bounds__(256) void k_bhist(const int* __restrict__ dst, int* __restrict__ bcnt, int e) {
    __shared__ int lh[256];
    int t = threadIdx.x;
    lh[t] = 0;
    __syncthreads();
    for (int i = blockIdx.x * 256 + t; i < e; i += gridDim.x * 256)
        atomicAdd(&lh[dst[i] >> 8], 1);
    __syncthreads();
    if (lh[t] > 0) atomicAdd(&bcnt[t], lh[t]);
}

// single block: exclusive scans of edge counts (bebase) and edge+selfloop counts (bcbase);
// init scatter cursors; rowptr[N] = E+N
__global__ __launch_bounds__(256) void k_bscan(const int* __restrict__ bcnt, int* __restrict__ bebase,
                                               int* __restrict__ bcbase, int* __restrict__ bcur,
                                               int* __restrict__ rowptr, int nbk, int n, int e) {
    __shared__ int se[256], sc[256];
    int t = threadIdx.x;
    int ec = (t < nbk) ? bcnt[t] : 0;
    int nodes = 0;
    if (t < nbk) {
        nodes = n - t * 256;
        if (nodes > 256) nodes = 256;
        if (nodes < 0) nodes = 0;
    }
    se[t] = ec;
    sc[t] = ec + nodes;
    __syncthreads();
    for (int off = 1; off < 256; off <<= 1) {
        int ve = (t >= off) ? se[t - off] : 0;
        int vc = (t >= off) ? sc[t - off] : 0;
        __syncthreads();
        se[t] += ve;
        sc[t] += vc;
        __syncthreads();
    }
    if (t < nbk) {
        bebase[t] = se[t] - ec;
        bcbase[t] = sc[t] - (ec + nodes);
        bcur[t]   = se[t] - ec;
    }
    if (t == 0) {
        bebase[nbk] = e;
        rowptr[n] = e + n;
    }
}

// scatter edges into bucket-contiguous storage; one global atomic per (block,bucket)
__global__ __launch_bounds__(256) void k_bscatter(const int* __restrict__ src, const int* __restrict__ dst,
                                                  int* __restrict__ bcur, int2* __restrict__ bedges, int e) {
    __shared__ int lh[256];
    __shared__ int gbase[256];
    int t = threadIdx.x;
    lh[t] = 0;
    __syncthreads();
    int base = blockIdx.x * 4096;
    int s_[16], d_[16];
#pragma unroll
    for (int u = 0; u < 16; ++u) {
        int j = base + u * 256 + t;
        if (j < e) {
            s_[u] = src[j];
            d_[u] = dst[j];
            atomicAdd(&lh[d_[u] >> 8], 1);
        } else {
            d_[u] = -1;
        }
    }
    __syncthreads();
    if (lh[t] > 0) gbase[t] = atomicAdd(&bcur[t], lh[t]);
    __syncthreads();
    lh[t] = 0;  // reuse as local cursor
    __syncthreads();
#pragma unroll
    for (int u = 0; u < 16; ++u) {
        if (d_[u] >= 0) {
            int bk = d_[u] >> 8;
            int lpos = atomicAdd(&lh[bk], 1);
            bedges[gbase[bk] + lpos] = make_int2(s_[u], d_[u]);
        }
    }
}

// one block per bucket: per-node histogram + scan in LDS -> rowptr/dinv; localized CSR scatter
__global__ __launch_bounds__(256) void k_bcsr(const int2* __restrict__ bedges, const int* __restrict__ bebase,
                                              const int* __restrict__ bcbase, int* __restrict__ rowptr,
                                              float* __restrict__ dinv, int* __restrict__ csr_s, int n) {
    __shared__ int lh[256], lcur[256];
    int b = blockIdx.x, t = threadIdx.x;
    int n0 = b << 8;
    int nb = n - n0; if (nb > 256) nb = 256;
    int e0 = bebase[b], e1 = bebase[b + 1];
    int cb = bcbase[b];
    lh[t] = 0;
    __syncthreads();
    for (int i = e0 + t; i < e1; i += 256)
        atomicAdd(&lh[bedges[i].y - n0], 1);
    __syncthreads();
    int deg = (t < nb) ? (lh[t] + 1) : 0;  // +1 self-loop
    __syncthreads();
    lh[t] = deg;
    __syncthreads();
    for (int off = 1; off < 256; off <<= 1) {
        int v = (t >= off) ? lh[t - off] : 0;
        __syncthreads();
        lh[t] += v;
        __syncthreads();
    }
    int lrp = lh[t] - deg;  // exclusive
    if (t < nb) {
        rowptr[n0 + t] = cb + lrp;
        dinv[n0 + t] = rsqrtf((float)deg);
    }
    lcur[t] = lrp;
    __syncthreads();
    for (int i = e0 + t; i < e1; i += 256) {
        int2 ed = bedges[i];
        int pos = cb + atomicAdd(&lcur[ed.y - n0], 1);
        csr_s[pos] = ed.x;
    }
    if (t < nb) {
        int pos = cb + atomicAdd(&lcur[t], 1);
        csr_s[pos] = n0 + t;  // self-loop
    }
}

// ================= fp32 -> fp16 conversion (8 elems/thread) =================
__global__ __launch_bounds__(256) void k_cvt(const float* __restrict__ X, __half* __restrict__ Y, int n8) {
    int i = blockIdx.x * 256 + threadIdx.x;
    if (i >= n8) return;
    float4 v0 = *(const float4*)&X[(size_t)i * 8];
    float4 v1 = *(const float4*)&X[(size_t)i * 8 + 4];
    ushort8 o;
    o[0] = __half_as_ushort(__float2half(v0.x));
    o[1] = __half_as_ushort(__float2half(v0.y));
    o[2] = __half_as_ushort(__float2half(v0.z));
    o[3] = __half_as_ushort(__float2half(v0.w));
    o[4] = __half_as_ushort(__float2half(v1.x));
    o[5] = __half_as_ushort(__float2half(v1.y));
    o[6] = __half_as_ushort(__float2half(v1.z));
    o[7] = __half_as_ushort(__float2half(v1.w));
    *(ushort8*)&Y[(size_t)i * 8] = o;
}

// ================= W -> fragment-ordered fp16 pack =================
// B-fragment for mfma_f32_16x16x32_f16: lane l, elem i -> B[k][col],
//   k = kc*32 + (l>>4)*8 + i, col = nt*16 + (l&15)
__global__ __launch_bounds__(256) void k_wprep(const float* __restrict__ W0, const float* __restrict__ Wh,
                                               __half* __restrict__ WP) {
    int layer = blockIdx.x;
    const float* W = (layer == 0) ? W0 : Wh + (size_t)(layer - 1) * 16384;
    __half* out = WP + (size_t)layer * 16384;
    int t = threadIdx.x;
    for (int u = 0; u < 64; ++u) {
        int o = u * 256 + t;
        int i  = o & 7;
        int l  = (o >> 3) & 63;
        int kc = (o >> 9) & 3;
        int nt = o >> 11;
        int k   = kc * 32 + ((l >> 4) << 3) + i;
        int col = nt * 16 + (l & 15);
        out[o] = __float2half(W[k * 128 + col]);
    }
}

// ================= MFMA GEMM: O[r,:] = fp16( dinv[r] * (H[r,:] @ W) ) =================
__global__ __launch_bounds__(256) void k_gemm(const __half* __restrict__ H, const __half* __restrict__ WP,
                                              const float* __restrict__ dinv, __half* __restrict__ O,
                                              int n) {
    __shared__ __half wl[16384];
    const int t = threadIdx.x;
#pragma unroll
    for (int u = 0; u < 8; ++u) {
        int idx = (u * 256 + t) * 8;
        *(ushort8*)&wl[idx] = *(const ushort8*)&WP[idx];
    }
    const int wid = t >> 6, l = t & 63;
    const int row0 = blockIdx.x * 128 + wid * 32;
    const int ar = l & 15, g = l >> 4;

    f16x8 a[2][4];
    float dv[2][4];
#pragma unroll
    for (int mt = 0; mt < 2; ++mt) {
        int row = row0 + mt * 16 + ar;
        int rc = min(row, n - 1);
#pragma unroll
        for (int kc = 0; kc < 4; ++kc)
            a[mt][kc] = *(const f16x8*)&H[(size_t)rc * 128 + kc * 32 + g * 8];
#pragma unroll
        for (int r = 0; r < 4; ++r) {
            int orow = row0 + mt * 16 + g * 4 + r;
            dv[mt][r] = dinv[min(orow, n - 1)];
        }
    }
    __syncthreads();

#pragma unroll
    for (int nt = 0; nt < 8; ++nt) {
        f16x8 b[4];
#pragma unroll
        for (int kc = 0; kc < 4; ++kc)
            b[kc] = *(f16x8*)&wl[((nt * 4 + kc) * 64 + l) * 8];
#pragma unroll
        for (int mt = 0; mt < 2; ++mt) {
            f32x4 acc = {0.f, 0.f, 0.f, 0.f};
#pragma unroll
            for (int kc = 0; kc < 4; ++kc)
                acc = __builtin_amdgcn_mfma_f32_16x16x32_f16(a[mt][kc], b[kc], acc, 0, 0, 0);
#pragma unroll
            for (int r = 0; r < 4; ++r) {
                int orow = row0 + mt * 16 + g * 4 + r;
                if (orow < n)
                    O[(size_t)orow * 128 + nt * 16 + ar] = __float2half(acc[r] * dv[mt][r]);
            }
        }
    }
}

// ================= aggregation: h[v] = relu(dinv[v]*sum XW[src] + bias) -> fp16 =================
// one wave per node; neighbor indices loaded coalesced (lane j -> cs[s+j]) then __shfl-broadcast
__global__ __launch_bounds__(256) void k_agg(const __half* __restrict__ XW, const int* __restrict__ cs,
                                             const int* __restrict__ rp, const float* __restrict__ dinv,
                                             const float* __restrict__ bias, __half* __restrict__ Hn, int n) {
    int wid  = (blockIdx.x * 256 + threadIdx.x) >> 6;
    int lane = threadIdx.x & 63;
    if (wid >= n) return;
    int s = rp[wid], e = rp[wid + 1];
    const __half2* X2 = (const __half2*)XW;
    float a0 = 0.f, a1 = 0.f, b0v = 0.f, b1v = 0.f, c0v = 0.f, c1v = 0.f, d0v = 0.f, d1v = 0.f;
    for (int base = s; base < e; base += 64) {
        int m = e - base;
        if (m > 64) m = 64;
        int myi = (lane < m) ? cs[base + lane] : 0;
        int j = 0;
        for (; j + 4 <= m; j += 4) {
            int i0 = __shfl(myi, j);
            int i1 = __shfl(myi, j + 1);
            int i2 = __shfl(myi, j + 2);
            int i3 = __shfl(myi, j + 3);
            float2 v0 = __half22float2(X2[(size_t)i0 * 64 + lane]);
            float2 v1 = __half22float2(X2[(size_t)i1 * 64 + lane]);
            float2 v2 = __half22float2(X2[(size_t)i2 * 64 + lane]);
            float2 v3 = __half22float2(X2[(size_t)i3 * 64 + lane]);
            a0 += v0.x; a1 += v0.y;
            b0v += v1.x; b1v += v1.y;
            c0v += v2.x; c1v += v2.y;
            d0v += v3.x; d1v += v3.y;
        }
        for (; j < m; ++j) {
            int i0 = __shfl(myi, j);
            float2 v = __half22float2(X2[(size_t)i0 * 64 + lane]);
            a0 += v.x; a1 += v.y;
        }
    }
    a0 += b0v + c0v + d0v;
    a1 += b1v + c1v + d1v;
    float dvv = dinv[wid];
    int f = lane * 2;
    a0 = fmaxf(fmaf(a0, dvv, bias[f]),     0.f);
    a1 = fmaxf(fmaf(a1, dvv, bias[f + 1]), 0.f);
    ((__half2*)Hn)[(size_t)wid * 64 + lane] = __floats2half2_rn(a0, a1);
}

// ================= pooling =================

__global__ __launch_bounds__(256) void k_bounds(const int* __restrict__ batch, int* __restrict__ startg,
                                                int n, int g) {
    int i = blockIdx.x * 256 + threadIdx.x;
    if (i >= n) return;
    int b = batch[i];
    if (i == 0) {
        for (int q = 0; q <= b; ++q) startg[q] = 0;
    } else {
        int pb = batch[i - 1];
        for (int q = pb + 1; q <= b; ++q) startg[q] = i;
    }
    if (i == n - 1) {
        for (int q = b + 1; q <= g; ++q) startg[q] = n;
    }
}

__global__ __launch_bounds__(256) void k_pool(const __half* __restrict__ H, const int* __restrict__ startg,
                                              float* __restrict__ P) {
    __shared__ float ss[256], sm[256];
    int g = blockIdx.x;
    int t = threadIdx.x;
    int f = t & 127, h = t >> 7;
    int s = startg[g], e = startg[g + 1];
    float sum = 0.f, mx = 0.f;  // h >= 0 after relu; 0-init reproduces the isfinite guard
    for (int nidx = s + h; nidx < e; nidx += 2) {
        float v = __half2float(H[(size_t)nidx * 128 + f]);
        sum += v;
        mx = fmaxf(mx, v);
    }
    ss[t] = sum;
    sm[t] = mx;
    __syncthreads();
    if (t < 128) {
        sum = ss[t] + ss[t + 128];
        mx = fmaxf(sm[t], sm[t + 128]);
        float cnt = (float)(e - s);
        P[(size_t)g * 384 + f]       = sum;
        P[(size_t)g * 384 + 128 + f] = sum / fmaxf(cnt, 1.f);
        P[(size_t)g * 384 + 256 + f] = mx;
    }
}

// ================= head: lin1 + relu + lin2 + log_softmax =================
__global__ __launch_bounds__(128) void k_head(const float* __restrict__ P,
                                              const float* __restrict__ w1, const float* __restrict__ b1,
                                              const float* __restrict__ w2, const float* __restrict__ b2,
                                              float* __restrict__ out) {
    __shared__ float gv[384];
    __shared__ float o1[128];
    int g = blockIdx.x, t = threadIdx.x;
    gv[t]       = P[(size_t)g * 384 + t];
    gv[t + 128] = P[(size_t)g * 384 + 128 + t];
    gv[t + 256] = P[(size_t)g * 384 + 256 + t];
    __syncthreads();
    float acc = b1[t];
#pragma unroll 8
    for (int k = 0; k < 384; ++k) acc = fmaf(gv[k], w1[k * 128 + t], acc);
    o1[t] = fmaxf(acc, 0.f);
    __syncthreads();
    if (t < 64) {
        float p0 = o1[t] * w2[t * 2 + 0] + o1[t + 64] * w2[(t + 64) * 2 + 0];
        float p1 = o1[t] * w2[t * 2 + 1] + o1[t + 64] * w2[(t + 64) * 2 + 1];
        for (int off = 32; off > 0; off >>= 1) {
            p0 += __shfl_down(p0, off);
            p1 += __shfl_down(p1, off);
        }
        if (t == 0) {
            float l0 = p0 + b2[0], l1 = p1 + b2[1];
            float m = fmaxf(l0, l1);
            float lse = m + logf(expf(l0 - m) + expf(l1 - m));
            out[g * 2 + 0] = l0 - lse;
            out[g * 2 + 1] = l1 - lse;
        }
    }
}

// ================= launcher =================

extern "C" void kernel_launch(void* const* d_in, const int* in_sizes, int n_in,
                              void* d_out, int out_size, void* d_ws, size_t ws_size,
                              hipStream_t stream) {
    const float* x     = (const float*)d_in[0];
    const int*   ei    = (const int*)d_in[1];
    const int*   batch = (const int*)d_in[2];
    const float* W0    = (const float*)d_in[3];
    const float* b0    = (const float*)d_in[4];
    const float* Wh    = (const float*)d_in[5];
    const float* bh    = (const float*)d_in[6];
    const float* l1w   = (const float*)d_in[7];
    const float* l1b   = (const float*)d_in[8];
    const float* l2w   = (const float*)d_in[9];
    const float* l2b   = (const float*)d_in[10];
    float* out = (float*)d_out;

    const int N  = in_sizes[0] / 128;
    const int E  = in_sizes[1] / 2;
    const int G  = out_size / 2;
    const int LX = in_sizes[5] / (128 * 128);
    const int NB = (N + 255) / 256;  // buckets (<=256 assumed, N<=65536)

    const int* src = ei;
    const int* dst = ei + E;

    char* p = (char*)d_ws;
    auto alloc = [&](size_t bytes) -> void* {
        void* r = (void*)p;
        p += (bytes + 255) & ~(size_t)255;
        return r;
    };
    int*    rowptr = (int*)alloc((size_t)(N + 1) * 4);
    float*  dinv   = (float*)alloc((size_t)N * 4);
    int*    bcnt   = (int*)alloc(1040);
    int*    bebase = (int*)alloc(1040);
    int*    bcbase = (int*)alloc(1040);
    int*    bcur   = (int*)alloc(1040);
    int*    startg = (int*)alloc((size_t)(G + 1) * 4);
    int*    csr_s  = (int*)alloc((size_t)(E + N) * 4);
    int2*   bedges = (int2*)alloc((size_t)E * 8);
    __half* x16    = (__half*)alloc((size_t)N * 128 * 2);
    __half* h16    = (__half*)alloc((size_t)N * 128 * 2);
    __half* xw16   = (__half*)alloc((size_t)N * 128 * 2);
    __half* wp     = (__half*)alloc((size_t)(LX + 1) * 16384 * 2);
    float*  pooled = (float*)alloc((size_t)G * 384 * 4);

    const int nbN = (N + 255) / 256;

    // --- weight pack + input conversion (independent of CSR) ---
    k_wprep<<<LX + 1, 256, 0, stream>>>(W0, Wh, wp);
    k_cvt<<<(N * 16 + 255) / 256, 256, 0, stream>>>(x, x16, N * 16);  // N*128/8 items

    // --- bucketed CSR setup (once per launch, reused by all layers) ---
    k_zero256<<<1, 256, 0, stream>>>(bcnt);
    k_bhist<<<NB, 256, 0, stream>>>(dst, bcnt, E);
    k_bscan<<<1, 256, 0, stream>>>(bcnt, bebase, bcbase, bcur, rowptr, NB, N, E);
    k_bscatter<<<(E + 4095) / 4096, 256, 0, stream>>>(src, dst, bcur, bedges, E);
    k_bcsr<<<NB, 256, 0, stream>>>(bedges, bebase, bcbase, rowptr, dinv, csr_s, N);

    // --- 4 GCN layers ---
    const int gemmBlocks = (N + 127) / 128;
    const int aggBlocks  = (N + 3) / 4;

    k_gemm<<<gemmBlocks, 256, 0, stream>>>(x16, wp, dinv, xw16, N);
    k_agg<<<aggBlocks, 256, 0, stream>>>(xw16, csr_s, rowptr, dinv, b0, h16, N);
    for (int l = 0; l < LX; ++l) {
        k_gemm<<<gemmBlocks, 256, 0, stream>>>(h16, wp + (size_t)(l + 1) * 16384, dinv, xw16, N);
        k_agg<<<aggBlocks, 256, 0, stream>>>(xw16, csr_s, rowptr, dinv, bh + (size_t)l * 128, h16, N);
    }

    // --- pooling + head ---
    k_bounds<<<nbN, 256, 0, stream>>>(batch, startg, N, G);
    k_pool<<<G, 256, 0, stream>>>(h16, startg, pooled);
    k_head<<<G, 128, 0, stream>>>(pooled, l1w, l1b, l2w, l2b, out);
}

// Round 6
// 279.359 us; speedup vs baseline: 2.2116x; 1.0047x over previous
//
#include <hip/hip_runtime.h>
#include <hip/hip_fp16.h>
#include <cstddef>

typedef _Float16 f16x8 __attribute__((ext_vector_type(8)));
typedef float f32x4 __attribute__((ext_vector_type(4)));
typedef unsigned short ushort8 __attribute__((ext_vector_type(8)));

// ================= bucketed CSR construction =================
// Buckets of 256 consecutive dst nodes (bucket = dst>>8). NB = ceil(N/256) <= 256.

// per-block LDS histogram of dst>>8, flushed with 256 global atomics per block
__global__ __launch_bounds__(256) void k_bhist(const int* __restrict__ dst, int* __restrict__ bcnt, int e) {
    __shared__ int lh[256];
    int t = threadIdx.x;
    lh[t] = 0;
    __syncthreads();
    for (int i = blockIdx.x * 256 + t; i < e; i += gridDim.x * 256)
        atomicAdd(&lh[dst[i] >> 8], 1);
    __syncthreads();
    if (lh[t] > 0) atomicAdd(&bcnt[t], lh[t]);
}

// single block: exclusive scans of edge counts (bebase) and edge+selfloop counts (bcbase);
// init scatter cursors; rowptr[N] = E+N
__global__ __launch_bounds__(256) void k_bscan(const int* __restrict__ bcnt, int* __restrict__ bebase,
                                               int* __restrict__ bcbase, int* __restrict__ bcur,
                                               int* __restrict__ rowptr, int nbk, int n, int e) {
    __shared__ int se[256], sc[256];
    int t = threadIdx.x;
    int ec = (t < nbk) ? bcnt[t] : 0;
    int nodes = 0;
    if (t < nbk) {
        nodes = n - t * 256;
        if (nodes > 256) nodes = 256;
        if (nodes < 0) nodes = 0;
    }
    se[t] = ec;
    sc[t] = ec + nodes;
    __syncthreads();
    for (int off = 1; off < 256; off <<= 1) {
        int ve = (t >= off) ? se[t - off] : 0;
        int vc = (t >= off) ? sc[t - off] : 0;
        __syncthreads();
        se[t] += ve;
        sc[t] += vc;
        __syncthreads();
    }
    if (t < nbk) {
        bebase[t] = se[t] - ec;
        bcbase[t] = sc[t] - (ec + nodes);
        bcur[t]   = se[t] - ec;
    }
    if (t == 0) {
        bebase[nbk] = e;
        rowptr[n] = e + n;
    }
}

// scatter edges into bucket-contiguous storage; one global atomic per (block,bucket)
__global__ __launch_bounds__(256) void k_bscatter(const int* __restrict__ src, const int* __restrict__ dst,
                                                  int* __restrict__ bcur, int2* __restrict__ bedges, int e) {
    __shared__ int lh[256];
    __shared__ int gbase[256];
    int t = threadIdx.x;
    lh[t] = 0;
    __syncthreads();
    int base = blockIdx.x * 4096;
    int s_[16], d_[16];
#pragma unroll
    for (int u = 0; u < 16; ++u) {
        int j = base + u * 256 + t;
        if (j < e) {
            s_[u] = src[j];
            d_[u] = dst[j];
            atomicAdd(&lh[d_[u] >> 8], 1);
        } else {
            d_[u] = -1;
        }
    }
    __syncthreads();
    if (lh[t] > 0) gbase[t] = atomicAdd(&bcur[t], lh[t]);
    __syncthreads();
    lh[t] = 0;  // reuse as local cursor
    __syncthreads();
#pragma unroll
    for (int u = 0; u < 16; ++u) {
        if (d_[u] >= 0) {
            int bk = d_[u] >> 8;
            int lpos = atomicAdd(&lh[bk], 1);
            bedges[gbase[bk] + lpos] = make_int2(s_[u], d_[u]);
        }
    }
}

// one block per bucket: per-node histogram + scan in LDS -> rowptr/dinv; localized CSR scatter
__global__ __launch_bounds__(256) void k_bcsr(const int2* __restrict__ bedges, const int* __restrict__ bebase,
                                              const int* __restrict__ bcbase, int* __restrict__ rowptr,
                                              float* __restrict__ dinv, int* __restrict__ csr_s, int n) {
    __shared__ int lh[256], lcur[256];
    int b = blockIdx.x, t = threadIdx.x;
    int n0 = b << 8;
    int nb = n - n0; if (nb > 256) nb = 256;
    int e0 = bebase[b], e1 = bebase[b + 1];
    int cb = bcbase[b];
    lh[t] = 0;
    __syncthreads();
    for (int i = e0 + t; i < e1; i += 256)
        atomicAdd(&lh[bedges[i].y - n0], 1);
    __syncthreads();
    int deg = (t < nb) ? (lh[t] + 1) : 0;  // +1 self-loop
    __syncthreads();
    lh[t] = deg;
    __syncthreads();
    for (int off = 1; off < 256; off <<= 1) {
        int v = (t >= off) ? lh[t - off] : 0;
        __syncthreads();
        lh[t] += v;
        __syncthreads();
    }
    int lrp = lh[t] - deg;  // exclusive
    if (t < nb) {
        rowptr[n0 + t] = cb + lrp;
        dinv[n0 + t] = rsqrtf((float)deg);
    }
    lcur[t] = lrp;
    __syncthreads();
    for (int i = e0 + t; i < e1; i += 256) {
        int2 ed = bedges[i];
        int pos = cb + atomicAdd(&lcur[ed.y - n0], 1);
        csr_s[pos] = ed.x;
    }
    if (t < nb) {
        int pos = cb + atomicAdd(&lcur[t], 1);
        csr_s[pos] = n0 + t;  // self-loop
    }
}

// ================= W -> fragment-ordered fp16 pack (+ bcnt zeroing in extra block) =================
// B-fragment for mfma_f32_16x16x32_f16: lane l, elem i -> B[k][col],
//   k = kc*32 + (l>>4)*8 + i, col = nt*16 + (l&15)
__global__ __launch_bounds__(256) void k_wprep(const float* __restrict__ W0, const float* __restrict__ Wh,
                                               __half* __restrict__ WP, int* __restrict__ bcnt, int nlayers) {
    int layer = blockIdx.x;
    int t = threadIdx.x;
    if (layer >= nlayers) {  // extra block: zero the bucket counters
        bcnt[t] = 0;
        return;
    }
    const float* W = (layer == 0) ? W0 : Wh + (size_t)(layer - 1) * 16384;
    __half* out = WP + (size_t)layer * 16384;
    for (int u = 0; u < 64; ++u) {
        int o = u * 256 + t;
        int i  = o & 7;
        int l  = (o >> 3) & 63;
        int kc = (o >> 9) & 3;
        int nt = o >> 11;
        int k   = kc * 32 + ((l >> 4) << 3) + i;
        int col = nt * 16 + (l & 15);
        out[o] = __float2half(W[k * 128 + col]);
    }
}

// ================= MFMA GEMM: O[r,:] = fp16( dinv[r] * (H[r,:] @ W) ) =================
// 256 threads = 4 waves; block tile 128 rows; A from global fp16, B from LDS-packed W'
__global__ __launch_bounds__(256) void k_gemm(const __half* __restrict__ H, const __half* __restrict__ WP,
                                              const float* __restrict__ dinv, __half* __restrict__ O,
                                              int n) {
    __shared__ __half wl[16384];
    const int t = threadIdx.x;
#pragma unroll
    for (int u = 0; u < 8; ++u) {
        int idx = (u * 256 + t) * 8;
        *(ushort8*)&wl[idx] = *(const ushort8*)&WP[idx];
    }
    const int wid = t >> 6, l = t & 63;
    const int row0 = blockIdx.x * 128 + wid * 32;
    const int ar = l & 15, g = l >> 4;

    f16x8 a[2][4];
    float dv[2][4];
#pragma unroll
    for (int mt = 0; mt < 2; ++mt) {
        int row = row0 + mt * 16 + ar;
        int rc = min(row, n - 1);
#pragma unroll
        for (int kc = 0; kc < 4; ++kc)
            a[mt][kc] = *(const f16x8*)&H[(size_t)rc * 128 + kc * 32 + g * 8];
#pragma unroll
        for (int r = 0; r < 4; ++r) {
            int orow = row0 + mt * 16 + g * 4 + r;
            dv[mt][r] = dinv[min(orow, n - 1)];
        }
    }
    __syncthreads();

#pragma unroll
    for (int nt = 0; nt < 8; ++nt) {
        f16x8 b[4];
#pragma unroll
        for (int kc = 0; kc < 4; ++kc)
            b[kc] = *(f16x8*)&wl[((nt * 4 + kc) * 64 + l) * 8];
#pragma unroll
        for (int mt = 0; mt < 2; ++mt) {
            f32x4 acc = {0.f, 0.f, 0.f, 0.f};
#pragma unroll
            for (int kc = 0; kc < 4; ++kc)
                acc = __builtin_amdgcn_mfma_f32_16x16x32_f16(a[mt][kc], b[kc], acc, 0, 0, 0);
#pragma unroll
            for (int r = 0; r < 4; ++r) {
                int orow = row0 + mt * 16 + g * 4 + r;
                if (orow < n)
                    O[(size_t)orow * 128 + nt * 16 + ar] = __float2half(acc[r] * dv[mt][r]);
            }
        }
    }
}

// same, but A read from fp32 input (layer 0) and converted in-register — removes the k_cvt pass
__global__ __launch_bounds__(256) void k_gemm32(const float* __restrict__ H, const __half* __restrict__ WP,
                                                const float* __restrict__ dinv, __half* __restrict__ O,
                                                int n) {
    __shared__ __half wl[16384];
    const int t = threadIdx.x;
#pragma unroll
    for (int u = 0; u < 8; ++u) {
        int idx = (u * 256 + t) * 8;
        *(ushort8*)&wl[idx] = *(const ushort8*)&WP[idx];
    }
    const int wid = t >> 6, l = t & 63;
    const int row0 = blockIdx.x * 128 + wid * 32;
    const int ar = l & 15, g = l >> 4;

    f16x8 a[2][4];
    float dv[2][4];
#pragma unroll
    for (int mt = 0; mt < 2; ++mt) {
        int row = row0 + mt * 16 + ar;
        int rc = min(row, n - 1);
#pragma unroll
        for (int kc = 0; kc < 4; ++kc) {
            float4 p0 = *(const float4*)&H[(size_t)rc * 128 + kc * 32 + g * 8];
            float4 p1 = *(const float4*)&H[(size_t)rc * 128 + kc * 32 + g * 8 + 4];
            f16x8 av;
            av[0] = (_Float16)p0.x; av[1] = (_Float16)p0.y; av[2] = (_Float16)p0.z; av[3] = (_Float16)p0.w;
            av[4] = (_Float16)p1.x; av[5] = (_Float16)p1.y; av[6] = (_Float16)p1.z; av[7] = (_Float16)p1.w;
            a[mt][kc] = av;
        }
#pragma unroll
        for (int r = 0; r < 4; ++r) {
            int orow = row0 + mt * 16 + g * 4 + r;
            dv[mt][r] = dinv[min(orow, n - 1)];
        }
    }
    __syncthreads();

#pragma unroll
    for (int nt = 0; nt < 8; ++nt) {
        f16x8 b[4];
#pragma unroll
        for (int kc = 0; kc < 4; ++kc)
            b[kc] = *(f16x8*)&wl[((nt * 4 + kc) * 64 + l) * 8];
#pragma unroll
        for (int mt = 0; mt < 2; ++mt) {
            f32x4 acc = {0.f, 0.f, 0.f, 0.f};
#pragma unroll
            for (int kc = 0; kc < 4; ++kc)
                acc = __builtin_amdgcn_mfma_f32_16x16x32_f16(a[mt][kc], b[kc], acc, 0, 0, 0);
#pragma unroll
            for (int r = 0; r < 4; ++r) {
                int orow = row0 + mt * 16 + g * 4 + r;
                if (orow < n)
                    O[(size_t)orow * 128 + nt * 16 + ar] = __float2half(acc[r] * dv[mt][r]);
            }
        }
    }
}

// ================= aggregation: h[v] = relu(dinv[v]*sum XW[src] + bias) -> fp16 =================
// one wave per node; coalesced index load + shfl broadcast; 8 independent gather chains in flight
__global__ __launch_bounds__(256) void k_agg(const __half* __restrict__ XW, const int* __restrict__ cs,
                                             const int* __restrict__ rp, const float* __restrict__ dinv,
                                             const float* __restrict__ bias, __half* __restrict__ Hn, int n) {
    int wid  = (blockIdx.x * 256 + threadIdx.x) >> 6;
    int lane = threadIdx.x & 63;
    if (wid >= n) return;
    int s = rp[wid], e = rp[wid + 1];
    const __half2* X2 = (const __half2*)XW;
    float ax[8], ay[8];
#pragma unroll
    for (int u = 0; u < 8; ++u) { ax[u] = 0.f; ay[u] = 0.f; }
    for (int base = s; base < e; base += 64) {
        int m = e - base;
        if (m > 64) m = 64;
        int myi = (lane < m) ? cs[base + lane] : 0;
        int j = 0;
        for (; j + 8 <= m; j += 8) {
            int idx[8];
#pragma unroll
            for (int u = 0; u < 8; ++u) idx[u] = __shfl(myi, j + u);
            float2 v[8];
#pragma unroll
            for (int u = 0; u < 8; ++u) v[u] = __half22float2(X2[(size_t)idx[u] * 64 + lane]);
#pragma unroll
            for (int u = 0; u < 8; ++u) { ax[u] += v[u].x; ay[u] += v[u].y; }
        }
        for (; j < m; ++j) {
            int i0 = __shfl(myi, j);
            float2 v = __half22float2(X2[(size_t)i0 * 64 + lane]);
            ax[j & 7] += v.x;
            ay[j & 7] += v.y;
        }
    }
    float a0 = (ax[0] + ax[1]) + (ax[2] + ax[3]) + ((ax[4] + ax[5]) + (ax[6] + ax[7]));
    float a1 = (ay[0] + ay[1]) + (ay[2] + ay[3]) + ((ay[4] + ay[5]) + (ay[6] + ay[7]));
    float dvv = dinv[wid];
    int f = lane * 2;
    a0 = fmaxf(fmaf(a0, dvv, bias[f]),     0.f);
    a1 = fmaxf(fmaf(a1, dvv, bias[f + 1]), 0.f);
    ((__half2*)Hn)[(size_t)wid * 64 + lane] = __floats2half2_rn(a0, a1);
}

// ================= fused pooling + head: one block per graph =================
// binary-search graph bounds in sorted batch; sum/mean/max pool; lin1+relu+lin2+log_softmax
__global__ __launch_bounds__(256) void k_poolhead(const __half* __restrict__ H, const int* __restrict__ batch,
                                                  const float* __restrict__ w1, const float* __restrict__ b1,
                                                  const float* __restrict__ w2, const float* __restrict__ b2,
                                                  float* __restrict__ out, int n) {
    __shared__ float ss[256], sm[256];
    __shared__ float gv[384];
    __shared__ float o1[128];
    __shared__ int bnd[2];
    int g = blockIdx.x, t = threadIdx.x;
    if (t < 2) {
        int key = g + t;
        int lo = 0, hi = n;
        while (lo < hi) {
            int mid = (lo + hi) >> 1;
            if (batch[mid] < key) lo = mid + 1; else hi = mid;
        }
        bnd[t] = lo;
    }
    __syncthreads();
    int s = bnd[0], e = bnd[1];
    int f = t & 127, h = t >> 7;
    float sum = 0.f, mx = 0.f;  // h >= 0 after relu; 0-init reproduces the isfinite guard
    for (int nidx = s + h; nidx < e; nidx += 2) {
        float v = __half2float(H[(size_t)nidx * 128 + f]);
        sum += v;
        mx = fmaxf(mx, v);
    }
    ss[t] = sum;
    sm[t] = mx;
    __syncthreads();
    if (t < 128) {
        sum = ss[t] + ss[t + 128];
        mx = fmaxf(sm[t], sm[t + 128]);
        float cnt = (float)(e - s);
        gv[t]       = sum;
        gv[128 + t] = sum / fmaxf(cnt, 1.f);
        gv[256 + t] = mx;
    }
    __syncthreads();
    if (t < 128) {
        float acc = b1[t];
#pragma unroll 8
        for (int k = 0; k < 384; ++k) acc = fmaf(gv[k], w1[k * 128 + t], acc);
        o1[t] = fmaxf(acc, 0.f);
    }
    __syncthreads();
    if (t < 64) {
        float p0 = o1[t] * w2[t * 2 + 0] + o1[t + 64] * w2[(t + 64) * 2 + 0];
        float p1 = o1[t] * w2[t * 2 + 1] + o1[t + 64] * w2[(t + 64) * 2 + 1];
        for (int off = 32; off > 0; off >>= 1) {
            p0 += __shfl_down(p0, off);
            p1 += __shfl_down(p1, off);
        }
        if (t == 0) {
            float l0 = p0 + b2[0], l1 = p1 + b2[1];
            float m = fmaxf(l0, l1);
            float lse = m + logf(expf(l0 - m) + expf(l1 - m));
            out[g * 2 + 0] = l0 - lse;
            out[g * 2 + 1] = l1 - lse;
        }
    }
}

// ================= launcher =================

extern "C" void kernel_launch(void* const* d_in, const int* in_sizes, int n_in,
                              void* d_out, int out_size, void* d_ws, size_t ws_size,
                              hipStream_t stream) {
    const float* x     = (const float*)d_in[0];
    const int*   ei    = (const int*)d_in[1];
    const int*   batch = (const int*)d_in[2];
    const float* W0    = (const float*)d_in[3];
    const float* b0    = (const float*)d_in[4];
    const float* Wh    = (const float*)d_in[5];
    const float* bh    = (const float*)d_in[6];
    const float* l1w   = (const float*)d_in[7];
    const float* l1b   = (const float*)d_in[8];
    const float* l2w   = (const float*)d_in[9];
    const float* l2b   = (const float*)d_in[10];
    float* out = (float*)d_out;

    const int N  = in_sizes[0] / 128;
    const int E  = in_sizes[1] / 2;
    const int G  = out_size / 2;
    const int LX = in_sizes[5] / (128 * 128);
    const int NB = (N + 255) / 256;  // buckets (<=256 assumed, N<=65536)

    const int* src = ei;
    const int* dst = ei + E;

    char* p = (char*)d_ws;
    auto alloc = [&](size_t bytes) -> void* {
        void* r = (void*)p;
        p += (bytes + 255) & ~(size_t)255;
        return r;
    };
    int*    rowptr = (int*)alloc((size_t)(N + 1) * 4);
    float*  dinv   = (float*)alloc((size_t)N * 4);
    int*    bcnt   = (int*)alloc(1040);
    int*    bebase = (int*)alloc(1040);
    int*    bcbase = (int*)alloc(1040);
    int*    bcur   = (int*)alloc(1040);
    int*    csr_s  = (int*)alloc((size_t)(E + N) * 4);
    int2*   bedges = (int2*)alloc((size_t)E * 8);
    __half* h16    = (__half*)alloc((size_t)N * 128 * 2);
    __half* xw16   = (__half*)alloc((size_t)N * 128 * 2);
    __half* wp     = (__half*)alloc((size_t)(LX + 1) * 16384 * 2);

    // --- weight pack (+ bcnt zero) ---
    k_wprep<<<LX + 2, 256, 0, stream>>>(W0, Wh, wp, bcnt, LX + 1);

    // --- bucketed CSR setup (once per launch, reused by all layers) ---
    k_bhist<<<NB, 256, 0, stream>>>(dst, bcnt, E);
    k_bscan<<<1, 256, 0, stream>>>(bcnt, bebase, bcbase, bcur, rowptr, NB, N, E);
    k_bscatter<<<(E + 4095) / 4096, 256, 0, stream>>>(src, dst, bcur, bedges, E);
    k_bcsr<<<NB, 256, 0, stream>>>(bedges, bebase, bcbase, rowptr, dinv, csr_s, N);

    // --- 4 GCN layers ---
    const int gemmBlocks = (N + 127) / 128;
    const int aggBlocks  = (N + 3) / 4;

    k_gemm32<<<gemmBlocks, 256, 0, stream>>>(x, wp, dinv, xw16, N);
    k_agg<<<aggBlocks, 256, 0, stream>>>(xw16, csr_s, rowptr, dinv, b0, h16, N);
    for (int l = 0; l < LX; ++l) {
        k_gemm<<<gemmBlocks, 256, 0, stream>>>(h16, wp + (size_t)(l + 1) * 16384, dinv, xw16, N);
        k_agg<<<aggBlocks, 256, 0, stream>>>(xw16, csr_s, rowptr, dinv, bh + (size_t)l * 128, h16, N);
    }

    // --- fused pooling + head ---
    k_poolhead<<<G, 256, 0, stream>>>(h16, batch, l1w, l1b, l2w, l2b, out, N);
}

// Round 7
// 263.316 us; speedup vs baseline: 2.3464x; 1.0609x over previous
//
#include <hip/hip_runtime.h>
#include <hip/hip_fp16.h>
#include <cstddef>

typedef _Float16 f16x8 __attribute__((ext_vector_type(8)));
typedef float f32x4 __attribute__((ext_vector_type(4)));
typedef unsigned short ushort8 __attribute__((ext_vector_type(8)));

// ================= bucketed CSR construction =================
// Buckets of 256 consecutive dst nodes (bucket = dst>>8). NB = ceil(N/256) <= 256.

// per-block LDS histogram of dst>>8, flushed with 256 global atomics per block
__global__ __launch_bounds__(256) void k_bhist(const int* __restrict__ dst, int* __restrict__ bcnt, int e) {
    __shared__ int lh[256];
    int t = threadIdx.x;
    lh[t] = 0;
    __syncthreads();
    for (int i = blockIdx.x * 256 + t; i < e; i += gridDim.x * 256)
        atomicAdd(&lh[dst[i] >> 8], 1);
    __syncthreads();
    if (lh[t] > 0) atomicAdd(&bcnt[t], lh[t]);
}

// single block: exclusive scans of edge counts (bebase) and edge+selfloop counts (bcbase);
// init scatter cursors; rowptr[N] = E+N
__global__ __launch_bounds__(256) void k_bscan(const int* __restrict__ bcnt, int* __restrict__ bebase,
                                               int* __restrict__ bcbase, int* __restrict__ bcur,
                                               int* __restrict__ rowptr, int nbk, int n, int e) {
    __shared__ int se[256], sc[256];
    int t = threadIdx.x;
    int ec = (t < nbk) ? bcnt[t] : 0;
    int nodes = 0;
    if (t < nbk) {
        nodes = n - t * 256;
        if (nodes > 256) nodes = 256;
        if (nodes < 0) nodes = 0;
    }
    se[t] = ec;
    sc[t] = ec + nodes;
    __syncthreads();
    for (int off = 1; off < 256; off <<= 1) {
        int ve = (t >= off) ? se[t - off] : 0;
        int vc = (t >= off) ? sc[t - off] : 0;
        __syncthreads();
        se[t] += ve;
        sc[t] += vc;
        __syncthreads();
    }
    if (t < nbk) {
        bebase[t] = se[t] - ec;
        bcbase[t] = sc[t] - (ec + nodes);
        bcur[t]   = se[t] - ec;
    }
    if (t == 0) {
        bebase[nbk] = e;
        rowptr[n] = e + n;
    }
}

// scatter edges into bucket-contiguous storage; one global atomic per (block,bucket)
__global__ __launch_bounds__(256) void k_bscatter(const int* __restrict__ src, const int* __restrict__ dst,
                                                  int* __restrict__ bcur, int2* __restrict__ bedges, int e) {
    __shared__ int lh[256];
    __shared__ int gbase[256];
    int t = threadIdx.x;
    lh[t] = 0;
    __syncthreads();
    int base = blockIdx.x * 4096;
    int s_[16], d_[16];
#pragma unroll
    for (int u = 0; u < 16; ++u) {
        int j = base + u * 256 + t;
        if (j < e) {
            s_[u] = src[j];
            d_[u] = dst[j];
            atomicAdd(&lh[d_[u] >> 8], 1);
        } else {
            d_[u] = -1;
        }
    }
    __syncthreads();
    if (lh[t] > 0) gbase[t] = atomicAdd(&bcur[t], lh[t]);
    __syncthreads();
    lh[t] = 0;  // reuse as local cursor
    __syncthreads();
#pragma unroll
    for (int u = 0; u < 16; ++u) {
        if (d_[u] >= 0) {
            int bk = d_[u] >> 8;
            int lpos = atomicAdd(&lh[bk], 1);
            bedges[gbase[bk] + lpos] = make_int2(s_[u], d_[u]);
        }
    }
}

// one block per bucket: per-node histogram + scan in LDS -> rowptr/dinv; localized CSR scatter
__global__ __launch_bounds__(256) void k_bcsr(const int2* __restrict__ bedges, const int* __restrict__ bebase,
                                              const int* __restrict__ bcbase, int* __restrict__ rowptr,
                                              float* __restrict__ dinv, int* __restrict__ csr_s, int n) {
    __shared__ int lh[256], lcur[256];
    int b = blockIdx.x, t = threadIdx.x;
    int n0 = b << 8;
    int nb = n - n0; if (nb > 256) nb = 256;
    int e0 = bebase[b], e1 = bebase[b + 1];
    int cb = bcbase[b];
    lh[t] = 0;
    __syncthreads();
    for (int i = e0 + t; i < e1; i += 256)
        atomicAdd(&lh[bedges[i].y - n0], 1);
    __syncthreads();
    int deg = (t < nb) ? (lh[t] + 1) : 0;  // +1 self-loop
    __syncthreads();
    lh[t] = deg;
    __syncthreads();
    for (int off = 1; off < 256; off <<= 1) {
        int v = (t >= off) ? lh[t - off] : 0;
        __syncthreads();
        lh[t] += v;
        __syncthreads();
    }
    int lrp = lh[t] - deg;  // exclusive
    if (t < nb) {
        rowptr[n0 + t] = cb + lrp;
        dinv[n0 + t] = rsqrtf((float)deg);
    }
    lcur[t] = lrp;
    __syncthreads();
    for (int i = e0 + t; i < e1; i += 256) {
        int2 ed = bedges[i];
        int pos = cb + atomicAdd(&lcur[ed.y - n0], 1);
        csr_s[pos] = ed.x;
    }
    if (t < nb) {
        int pos = cb + atomicAdd(&lcur[t], 1);
        csr_s[pos] = n0 + t;  // self-loop
    }
}

// ================= W -> fragment-ordered fp16 pack (+ bcnt zeroing in extra block) =================
// B-fragment for mfma_f32_16x16x32_f16: lane l, elem i -> B[k][col],
//   k = kc*32 + (l>>4)*8 + i, col = nt*16 + (l&15)
__global__ __launch_bounds__(256) void k_wprep(const float* __restrict__ W0, const float* __restrict__ Wh,
                                               __half* __restrict__ WP, int* __restrict__ bcnt, int nlayers) {
    int layer = blockIdx.x;
    int t = threadIdx.x;
    if (layer >= nlayers) {  // extra block: zero the bucket counters
        bcnt[t] = 0;
        return;
    }
    const float* W = (layer == 0) ? W0 : Wh + (size_t)(layer - 1) * 16384;
    __half* out = WP + (size_t)layer * 16384;
    for (int u = 0; u < 64; ++u) {
        int o = u * 256 + t;
        int i  = o & 7;
        int l  = (o >> 3) & 63;
        int kc = (o >> 9) & 3;
        int nt = o >> 11;
        int k   = kc * 32 + ((l >> 4) << 3) + i;
        int col = nt * 16 + (l & 15);
        out[o] = __float2half(W[k * 128 + col]);
    }
}

// ================= MFMA GEMM: O[r,:] = fp16( dinv[r] * (H[r,:] @ W) ) =================
// 256 threads = 4 waves; block tile 128 rows; A from global fp16, B from LDS-packed W'
__global__ __launch_bounds__(256) void k_gemm(const __half* __restrict__ H, const __half* __restrict__ WP,
                                              const float* __restrict__ dinv, __half* __restrict__ O,
                                              int n) {
    __shared__ __half wl[16384];
    const int t = threadIdx.x;
#pragma unroll
    for (int u = 0; u < 8; ++u) {
        int idx = (u * 256 + t) * 8;
        *(ushort8*)&wl[idx] = *(const ushort8*)&WP[idx];
    }
    const int wid = t >> 6, l = t & 63;
    const int row0 = blockIdx.x * 128 + wid * 32;
    const int ar = l & 15, g = l >> 4;

    f16x8 a[2][4];
    float dv[2][4];
#pragma unroll
    for (int mt = 0; mt < 2; ++mt) {
        int row = row0 + mt * 16 + ar;
        int rc = min(row, n - 1);
#pragma unroll
        for (int kc = 0; kc < 4; ++kc)
            a[mt][kc] = *(const f16x8*)&H[(size_t)rc * 128 + kc * 32 + g * 8];
#pragma unroll
        for (int r = 0; r < 4; ++r) {
            int orow = row0 + mt * 16 + g * 4 + r;
            dv[mt][r] = dinv[min(orow, n - 1)];
        }
    }
    __syncthreads();

#pragma unroll
    for (int nt = 0; nt < 8; ++nt) {
        f16x8 b[4];
#pragma unroll
        for (int kc = 0; kc < 4; ++kc)
            b[kc] = *(f16x8*)&wl[((nt * 4 + kc) * 64 + l) * 8];
#pragma unroll
        for (int mt = 0; mt < 2; ++mt) {
            f32x4 acc = {0.f, 0.f, 0.f, 0.f};
#pragma unroll
            for (int kc = 0; kc < 4; ++kc)
                acc = __builtin_amdgcn_mfma_f32_16x16x32_f16(a[mt][kc], b[kc], acc, 0, 0, 0);
#pragma unroll
            for (int r = 0; r < 4; ++r) {
                int orow = row0 + mt * 16 + g * 4 + r;
                if (orow < n)
                    O[(size_t)orow * 128 + nt * 16 + ar] = __float2half(acc[r] * dv[mt][r]);
            }
        }
    }
}

// same, but A read from fp32 input (layer 0) and converted in-register
__global__ __launch_bounds__(256) void k_gemm32(const float* __restrict__ H, const __half* __restrict__ WP,
                                                const float* __restrict__ dinv, __half* __restrict__ O,
                                                int n) {
    __shared__ __half wl[16384];
    const int t = threadIdx.x;
#pragma unroll
    for (int u = 0; u < 8; ++u) {
        int idx = (u * 256 + t) * 8;
        *(ushort8*)&wl[idx] = *(const ushort8*)&WP[idx];
    }
    const int wid = t >> 6, l = t & 63;
    const int row0 = blockIdx.x * 128 + wid * 32;
    const int ar = l & 15, g = l >> 4;

    f16x8 a[2][4];
    float dv[2][4];
#pragma unroll
    for (int mt = 0; mt < 2; ++mt) {
        int row = row0 + mt * 16 + ar;
        int rc = min(row, n - 1);
#pragma unroll
        for (int kc = 0; kc < 4; ++kc) {
            float4 p0 = *(const float4*)&H[(size_t)rc * 128 + kc * 32 + g * 8];
            float4 p1 = *(const float4*)&H[(size_t)rc * 128 + kc * 32 + g * 8 + 4];
            f16x8 av;
            av[0] = (_Float16)p0.x; av[1] = (_Float16)p0.y; av[2] = (_Float16)p0.z; av[3] = (_Float16)p0.w;
            av[4] = (_Float16)p1.x; av[5] = (_Float16)p1.y; av[6] = (_Float16)p1.z; av[7] = (_Float16)p1.w;
            a[mt][kc] = av;
        }
#pragma unroll
        for (int r = 0; r < 4; ++r) {
            int orow = row0 + mt * 16 + g * 4 + r;
            dv[mt][r] = dinv[min(orow, n - 1)];
        }
    }
    __syncthreads();

#pragma unroll
    for (int nt = 0; nt < 8; ++nt) {
        f16x8 b[4];
#pragma unroll
        for (int kc = 0; kc < 4; ++kc)
            b[kc] = *(f16x8*)&wl[((nt * 4 + kc) * 64 + l) * 8];
#pragma unroll
        for (int mt = 0; mt < 2; ++mt) {
            f32x4 acc = {0.f, 0.f, 0.f, 0.f};
#pragma unroll
            for (int kc = 0; kc < 4; ++kc)
                acc = __builtin_amdgcn_mfma_f32_16x16x32_f16(a[mt][kc], b[kc], acc, 0, 0, 0);
#pragma unroll
            for (int r = 0; r < 4; ++r) {
                int orow = row0 + mt * 16 + g * 4 + r;
                if (orow < n)
                    O[(size_t)orow * 128 + nt * 16 + ar] = __float2half(acc[r] * dv[mt][r]);
            }
        }
    }
}

// ================= aggregation: h[v] = relu(dinv[v]*sum XW[src] + bias) -> fp16 =================
// one wave per node; coalesced index load + shfl broadcast; 8 independent gather chains in flight
__global__ __launch_bounds__(256) void k_agg(const __half* __restrict__ XW, const int* __restrict__ cs,
                                             const int* __restrict__ rp, const float* __restrict__ dinv,
                                             const float* __restrict__ bias, __half* __restrict__ Hn, int n) {
    int wid  = (blockIdx.x * 256 + threadIdx.x) >> 6;
    int lane = threadIdx.x & 63;
    if (wid >= n) return;
    int s = rp[wid], e = rp[wid + 1];
    const __half2* X2 = (const __half2*)XW;
    float ax[8], ay[8];
#pragma unroll
    for (int u = 0; u < 8; ++u) { ax[u] = 0.f; ay[u] = 0.f; }
    for (int base = s; base < e; base += 64) {
        int m = e - base;
        if (m > 64) m = 64;
        int myi = (lane < m) ? cs[base + lane] : 0;
        int j = 0;
        for (; j + 8 <= m; j += 8) {
            int idx[8];
#pragma unroll
            for (int u = 0; u < 8; ++u) idx[u] = __shfl(myi, j + u);
            float2 v[8];
#pragma unroll
            for (int u = 0; u < 8; ++u) v[u] = __half22float2(X2[(size_t)idx[u] * 64 + lane]);
#pragma unroll
            for (int u = 0; u < 8; ++u) { ax[u] += v[u].x; ay[u] += v[u].y; }
        }
        for (; j < m; ++j) {
            int i0 = __shfl(myi, j);
            float2 v = __half22float2(X2[(size_t)i0 * 64 + lane]);
            ax[j & 7] += v.x;
            ay[j & 7] += v.y;
        }
    }
    float a0 = (ax[0] + ax[1]) + (ax[2] + ax[3]) + ((ax[4] + ax[5]) + (ax[6] + ax[7]));
    float a1 = (ay[0] + ay[1]) + (ay[2] + ay[3]) + ((ay[4] + ay[5]) + (ay[6] + ay[7]));
    float dvv = dinv[wid];
    int f = lane * 2;
    a0 = fmaxf(fmaf(a0, dvv, bias[f]),     0.f);
    a1 = fmaxf(fmaf(a1, dvv, bias[f + 1]), 0.f);
    ((__half2*)Hn)[(size_t)wid * 64 + lane] = __floats2half2_rn(a0, a1);
}

// ================= fused pooling + head: one block per graph =================
// vectorized pooling: thread (rg,fb) = (t>>4, t&15) reads f16x8 of features fb*8.. for rows s+rg::16
// -> 16 rows in flight, 16B/lane; LDS combine over row-groups; then lin1+relu+lin2+log_softmax
__global__ __launch_bounds__(256) void k_poolhead(const __half* __restrict__ H, const int* __restrict__ batch,
                                                  const float* __restrict__ w1, const float* __restrict__ b1,
                                                  const float* __restrict__ w2, const float* __restrict__ b2,
                                                  float* __restrict__ out, int n) {
    __shared__ float lsum[16][128];
    __shared__ float lmax[16][128];
    __shared__ float gv[384];
    __shared__ float o1[128];
    __shared__ int bnd[2];
    int g = blockIdx.x, t = threadIdx.x;
    if (t < 2) {
        int key = g + t;
        int lo = 0, hi = n;
        while (lo < hi) {
            int mid = (lo + hi) >> 1;
            if (batch[mid] < key) lo = mid + 1; else hi = mid;
        }
        bnd[t] = lo;
    }
    __syncthreads();
    const int s = bnd[0], e = bnd[1];
    const int rg = t >> 4, fb = t & 15;
    float sum8[8], max8[8];
#pragma unroll
    for (int j = 0; j < 8; ++j) { sum8[j] = 0.f; max8[j] = 0.f; }  // h>=0: 0-init == isfinite guard
    for (int r = s + rg; r < e; r += 16) {
        f16x8 v = *(const f16x8*)&H[(size_t)r * 128 + fb * 8];
#pragma unroll
        for (int j = 0; j < 8; ++j) {
            float x = (float)v[j];
            sum8[j] += x;
            max8[j] = fmaxf(max8[j], x);
        }
    }
#pragma unroll
    for (int j = 0; j < 8; ++j) {
        lsum[rg][fb * 8 + j] = sum8[j];
        lmax[rg][fb * 8 + j] = max8[j];
    }
    __syncthreads();
    if (t < 128) {
        float sum = 0.f, mx = 0.f;
#pragma unroll
        for (int r = 0; r < 16; ++r) {
            sum += lsum[r][t];
            mx = fmaxf(mx, lmax[r][t]);
        }
        float cnt = (float)(e - s);
        gv[t]       = sum;
        gv[128 + t] = sum / fmaxf(cnt, 1.f);
        gv[256 + t] = mx;
    }
    __syncthreads();
    if (t < 128) {
        float acc = b1[t];
#pragma unroll 8
        for (int k = 0; k < 384; ++k) acc = fmaf(gv[k], w1[k * 128 + t], acc);
        o1[t] = fmaxf(acc, 0.f);
    }
    __syncthreads();
    if (t < 64) {
        float p0 = o1[t] * w2[t * 2 + 0] + o1[t + 64] * w2[(t + 64) * 2 + 0];
        float p1 = o1[t] * w2[t * 2 + 1] + o1[t + 64] * w2[(t + 64) * 2 + 1];
        for (int off = 32; off > 0; off >>= 1) {
            p0 += __shfl_down(p0, off);
            p1 += __shfl_down(p1, off);
        }
        if (t == 0) {
            float l0 = p0 + b2[0], l1 = p1 + b2[1];
            float m = fmaxf(l0, l1);
            float lse = m + logf(expf(l0 - m) + expf(l1 - m));
            out[g * 2 + 0] = l0 - lse;
            out[g * 2 + 1] = l1 - lse;
        }
    }
}

// ================= launcher =================

extern "C" void kernel_launch(void* const* d_in, const int* in_sizes, int n_in,
                              void* d_out, int out_size, void* d_ws, size_t ws_size,
                              hipStream_t stream) {
    const float* x     = (const float*)d_in[0];
    const int*   ei    = (const int*)d_in[1];
    const int*   batch = (const int*)d_in[2];
    const float* W0    = (const float*)d_in[3];
    const float* b0    = (const float*)d_in[4];
    const float* Wh    = (const float*)d_in[5];
    const float* bh    = (const float*)d_in[6];
    const float* l1w   = (const float*)d_in[7];
    const float* l1b   = (const float*)d_in[8];
    const float* l2w   = (const float*)d_in[9];
    const float* l2b   = (const float*)d_in[10];
    float* out = (float*)d_out;

    const int N  = in_sizes[0] / 128;
    const int E  = in_sizes[1] / 2;
    const int G  = out_size / 2;
    const int LX = in_sizes[5] / (128 * 128);
    const int NB = (N + 255) / 256;  // buckets (<=256 assumed, N<=65536)

    const int* src = ei;
    const int* dst = ei + E;

    char* p = (char*)d_ws;
    auto alloc = [&](size_t bytes) -> void* {
        void* r = (void*)p;
        p += (bytes + 255) & ~(size_t)255;
        return r;
    };
    int*    rowptr = (int*)alloc((size_t)(N + 1) * 4);
    float*  dinv   = (float*)alloc((size_t)N * 4);
    int*    bcnt   = (int*)alloc(1040);
    int*    bebase = (int*)alloc(1040);
    int*    bcbase = (int*)alloc(1040);
    int*    bcur   = (int*)alloc(1040);
    int*    csr_s  = (int*)alloc((size_t)(E + N) * 4);
    int2*   bedges = (int2*)alloc((size_t)E * 8);
    __half* h16    = (__half*)alloc((size_t)N * 128 * 2);
    __half* xw16   = (__half*)alloc((size_t)N * 128 * 2);
    __half* wp     = (__half*)alloc((size_t)(LX + 1) * 16384 * 2);

    // --- weight pack (+ bcnt zero) ---
    k_wprep<<<LX + 2, 256, 0, stream>>>(W0, Wh, wp, bcnt, LX + 1);

    // --- bucketed CSR setup (once per launch, reused by all layers) ---
    k_bhist<<<NB, 256, 0, stream>>>(dst, bcnt, E);
    k_bscan<<<1, 256, 0, stream>>>(bcnt, bebase, bcbase, bcur, rowptr, NB, N, E);
    k_bscatter<<<(E + 4095) / 4096, 256, 0, stream>>>(src, dst, bcur, bedges, E);
    k_bcsr<<<NB, 256, 0, stream>>>(bedges, bebase, bcbase, rowptr, dinv, csr_s, N);

    // --- 4 GCN layers ---
    const int gemmBlocks = (N + 127) / 128;
    const int aggBlocks  = (N + 3) / 4;

    k_gemm32<<<gemmBlocks, 256, 0, stream>>>(x, wp, dinv, xw16, N);
    k_agg<<<aggBlocks, 256, 0, stream>>>(xw16, csr_s, rowptr, dinv, b0, h16, N);
    for (int l = 0; l < LX; ++l) {
        k_gemm<<<gemmBlocks, 256, 0, stream>>>(h16, wp + (size_t)(l + 1) * 16384, dinv, xw16, N);
        k_agg<<<aggBlocks, 256, 0, stream>>>(xw16, csr_s, rowptr, dinv, bh + (size_t)l * 128, h16, N);
    }

    // --- fused pooling + head ---
    k_poolhead<<<G, 256, 0, stream>>>(h16, batch, l1w, l1b, l2w, l2b, out, N);
}

// Round 8
// 249.504 us; speedup vs baseline: 2.4763x; 1.0554x over previous
//
#include <hip/hip_runtime.h>
#include <hip/hip_fp16.h>
#include <cstddef>

typedef _Float16 f16x8 __attribute__((ext_vector_type(8)));
typedef float f32x4 __attribute__((ext_vector_type(4)));
typedef unsigned short ushort8 __attribute__((ext_vector_type(8)));

// ================= bucketed CSR construction =================
// Buckets of 256 consecutive dst nodes (bucket = dst>>8). NB = ceil(N/256) <= 256.

// per-block LDS histogram of dst>>8, flushed with 256 global atomics per block
__global__ __launch_bounds__(256) void k_bhist(const int* __restrict__ dst, int* __restrict__ bcnt, int e) {
    __shared__ int lh[256];
    int t = threadIdx.x;
    lh[t] = 0;
    __syncthreads();
    for (int i = blockIdx.x * 256 + t; i < e; i += gridDim.x * 256)
        atomicAdd(&lh[dst[i] >> 8], 1);
    __syncthreads();
    if (lh[t] > 0) atomicAdd(&bcnt[t], lh[t]);
}

// single block: exclusive scans of edge counts (bebase) and edge+selfloop counts (bcbase);
// init scatter cursors; rowptr[N] = E+N
__global__ __launch_bounds__(256) void k_bscan(const int* __restrict__ bcnt, int* __restrict__ bebase,
                                               int* __restrict__ bcbase, int* __restrict__ bcur,
                                               int* __restrict__ rowptr, int nbk, int n, int e) {
    __shared__ int se[256], sc[256];
    int t = threadIdx.x;
    int ec = (t < nbk) ? bcnt[t] : 0;
    int nodes = 0;
    if (t < nbk) {
        nodes = n - t * 256;
        if (nodes > 256) nodes = 256;
        if (nodes < 0) nodes = 0;
    }
    se[t] = ec;
    sc[t] = ec + nodes;
    __syncthreads();
    for (int off = 1; off < 256; off <<= 1) {
        int ve = (t >= off) ? se[t - off] : 0;
        int vc = (t >= off) ? sc[t - off] : 0;
        __syncthreads();
        se[t] += ve;
        sc[t] += vc;
        __syncthreads();
    }
    if (t < nbk) {
        bebase[t] = se[t] - ec;
        bcbase[t] = sc[t] - (ec + nodes);
        bcur[t]   = se[t] - ec;
    }
    if (t == 0) {
        bebase[nbk] = e;
        rowptr[n] = e + n;
    }
}

// scatter edges into bucket-contiguous storage; one global atomic per (block,bucket)
// packed entry: (src<<8) | (dst & 255)   [dst-local is 8 bits by bucket construction]
__global__ __launch_bounds__(256) void k_bscatter(const int* __restrict__ src, const int* __restrict__ dst,
                                                  int* __restrict__ bcur, int* __restrict__ bedges, int e) {
    __shared__ int lh[256];
    __shared__ int gbase[256];
    int t = threadIdx.x;
    lh[t] = 0;
    __syncthreads();
    int base = blockIdx.x * 4096;
    int s_[16], d_[16];
#pragma unroll
    for (int u = 0; u < 16; ++u) {
        int j = base + u * 256 + t;
        if (j < e) {
            s_[u] = src[j];
            d_[u] = dst[j];
            atomicAdd(&lh[d_[u] >> 8], 1);
        } else {
            d_[u] = -1;
        }
    }
    __syncthreads();
    if (lh[t] > 0) gbase[t] = atomicAdd(&bcur[t], lh[t]);
    __syncthreads();
    lh[t] = 0;  // reuse as local cursor
    __syncthreads();
#pragma unroll
    for (int u = 0; u < 16; ++u) {
        if (d_[u] >= 0) {
            int bk = d_[u] >> 8;
            int lpos = atomicAdd(&lh[bk], 1);
            bedges[gbase[bk] + lpos] = (s_[u] << 8) | (d_[u] & 255);
        }
    }
}

// one block per bucket: per-node histogram + scan in LDS -> rowptr/dinv; localized CSR scatter
__global__ __launch_bounds__(256) void k_bcsr(const int* __restrict__ bedges, const int* __restrict__ bebase,
                                              const int* __restrict__ bcbase, int* __restrict__ rowptr,
                                              float* __restrict__ dinv, int* __restrict__ csr_s, int n) {
    __shared__ int lh[256], lcur[256];
    int b = blockIdx.x, t = threadIdx.x;
    int n0 = b << 8;
    int nb = n - n0; if (nb > 256) nb = 256;
    int e0 = bebase[b], e1 = bebase[b + 1];
    int cb = bcbase[b];
    lh[t] = 0;
    __syncthreads();
    for (int i = e0 + t; i < e1; i += 256)
        atomicAdd(&lh[bedges[i] & 255], 1);
    __syncthreads();
    int deg = (t < nb) ? (lh[t] + 1) : 0;  // +1 self-loop
    __syncthreads();
    lh[t] = deg;
    __syncthreads();
    for (int off = 1; off < 256; off <<= 1) {
        int v = (t >= off) ? lh[t - off] : 0;
        __syncthreads();
        lh[t] += v;
        __syncthreads();
    }
    int lrp = lh[t] - deg;  // exclusive
    if (t < nb) {
        rowptr[n0 + t] = cb + lrp;
        dinv[n0 + t] = rsqrtf((float)deg);
    }
    lcur[t] = lrp;
    __syncthreads();
    for (int i = e0 + t; i < e1; i += 256) {
        int ed = bedges[i];
        int pos = cb + atomicAdd(&lcur[ed & 255], 1);
        csr_s[pos] = (int)((unsigned)ed >> 8);
    }
    if (t < nb) {
        int pos = cb + atomicAdd(&lcur[t], 1);
        csr_s[pos] = n0 + t;  // self-loop
    }
}

// ================= W -> fragment-ordered fp16 pack (+ bcnt zeroing in extra block) =================
// B-fragment for mfma_f32_16x16x32_f16: lane l, elem i -> B[k][col],
//   k = kc*32 + (l>>4)*8 + i, col = nt*16 + (l&15)
__global__ __launch_bounds__(256) void k_wprep(const float* __restrict__ W0, const float* __restrict__ Wh,
                                               __half* __restrict__ WP, int* __restrict__ bcnt, int nlayers) {
    int layer = blockIdx.x;
    int t = threadIdx.x;
    if (layer >= nlayers) {  // extra block: zero the bucket counters
        bcnt[t] = 0;
        return;
    }
    const float* W = (layer == 0) ? W0 : Wh + (size_t)(layer - 1) * 16384;
    __half* out = WP + (size_t)layer * 16384;
    for (int u = 0; u < 64; ++u) {
        int o = u * 256 + t;
        int i  = o & 7;
        int l  = (o >> 3) & 63;
        int kc = (o >> 9) & 3;
        int nt = o >> 11;
        int k   = kc * 32 + ((l >> 4) << 3) + i;
        int col = nt * 16 + (l & 15);
        out[o] = __float2half(W[k * 128 + col]);
    }
}

// ================= MFMA GEMM: O[r,:] = fp16( dinv[r] * (H[r,:] @ W) ) =================
__global__ __launch_bounds__(256) void k_gemm(const __half* __restrict__ H, const __half* __restrict__ WP,
                                              const float* __restrict__ dinv, __half* __restrict__ O,
                                              int n) {
    __shared__ __half wl[16384];
    const int t = threadIdx.x;
#pragma unroll
    for (int u = 0; u < 8; ++u) {
        int idx = (u * 256 + t) * 8;
        *(ushort8*)&wl[idx] = *(const ushort8*)&WP[idx];
    }
    const int wid = t >> 6, l = t & 63;
    const int row0 = blockIdx.x * 128 + wid * 32;
    const int ar = l & 15, g = l >> 4;

    f16x8 a[2][4];
    float dv[2][4];
#pragma unroll
    for (int mt = 0; mt < 2; ++mt) {
        int row = row0 + mt * 16 + ar;
        int rc = min(row, n - 1);
#pragma unroll
        for (int kc = 0; kc < 4; ++kc)
            a[mt][kc] = *(const f16x8*)&H[(size_t)rc * 128 + kc * 32 + g * 8];
#pragma unroll
        for (int r = 0; r < 4; ++r) {
            int orow = row0 + mt * 16 + g * 4 + r;
            dv[mt][r] = dinv[min(orow, n - 1)];
        }
    }
    __syncthreads();

#pragma unroll
    for (int nt = 0; nt < 8; ++nt) {
        f16x8 b[4];
#pragma unroll
        for (int kc = 0; kc < 4; ++kc)
            b[kc] = *(f16x8*)&wl[((nt * 4 + kc) * 64 + l) * 8];
#pragma unroll
        for (int mt = 0; mt < 2; ++mt) {
            f32x4 acc = {0.f, 0.f, 0.f, 0.f};
#pragma unroll
            for (int kc = 0; kc < 4; ++kc)
                acc = __builtin_amdgcn_mfma_f32_16x16x32_f16(a[mt][kc], b[kc], acc, 0, 0, 0);
#pragma unroll
            for (int r = 0; r < 4; ++r) {
                int orow = row0 + mt * 16 + g * 4 + r;
                if (orow < n)
                    O[(size_t)orow * 128 + nt * 16 + ar] = __float2half(acc[r] * dv[mt][r]);
            }
        }
    }
}

// same, but A read from fp32 input (layer 0) and converted in-register
__global__ __launch_bounds__(256) void k_gemm32(const float* __restrict__ H, const __half* __restrict__ WP,
                                                const float* __restrict__ dinv, __half* __restrict__ O,
                                                int n) {
    __shared__ __half wl[16384];
    const int t = threadIdx.x;
#pragma unroll
    for (int u = 0; u < 8; ++u) {
        int idx = (u * 256 + t) * 8;
        *(ushort8*)&wl[idx] = *(const ushort8*)&WP[idx];
    }
    const int wid = t >> 6, l = t & 63;
    const int row0 = blockIdx.x * 128 + wid * 32;
    const int ar = l & 15, g = l >> 4;

    f16x8 a[2][4];
    float dv[2][4];
#pragma unroll
    for (int mt = 0; mt < 2; ++mt) {
        int row = row0 + mt * 16 + ar;
        int rc = min(row, n - 1);
#pragma unroll
        for (int kc = 0; kc < 4; ++kc) {
            float4 p0 = *(const float4*)&H[(size_t)rc * 128 + kc * 32 + g * 8];
            float4 p1 = *(const float4*)&H[(size_t)rc * 128 + kc * 32 + g * 8 + 4];
            f16x8 av;
            av[0] = (_Float16)p0.x; av[1] = (_Float16)p0.y; av[2] = (_Float16)p0.z; av[3] = (_Float16)p0.w;
            av[4] = (_Float16)p1.x; av[5] = (_Float16)p1.y; av[6] = (_Float16)p1.z; av[7] = (_Float16)p1.w;
            a[mt][kc] = av;
        }
#pragma unroll
        for (int r = 0; r < 4; ++r) {
            int orow = row0 + mt * 16 + g * 4 + r;
            dv[mt][r] = dinv[min(orow, n - 1)];
        }
    }
    __syncthreads();

#pragma unroll
    for (int nt = 0; nt < 8; ++nt) {
        f16x8 b[4];
#pragma unroll
        for (int kc = 0; kc < 4; ++kc)
            b[kc] = *(f16x8*)&wl[((nt * 4 + kc) * 64 + l) * 8];
#pragma unroll
        for (int mt = 0; mt < 2; ++mt) {
            f32x4 acc = {0.f, 0.f, 0.f, 0.f};
#pragma unroll
            for (int kc = 0; kc < 4; ++kc)
                acc = __builtin_amdgcn_mfma_f32_16x16x32_f16(a[mt][kc], b[kc], acc, 0, 0, 0);
#pragma unroll
            for (int r = 0; r < 4; ++r) {
                int orow = row0 + mt * 16 + g * 4 + r;
                if (orow < n)
                    O[(size_t)orow * 128 + nt * 16 + ar] = __float2half(acc[r] * dv[mt][r]);
            }
        }
    }
}

// ================= aggregation: h[v] = relu(dinv[v]*sum XW[src] + bias) -> fp16 =================
// one wave per node. Lane = (g=lane>>4, fs=lane&15): each load is f16x8 (16B) so one wave
// instruction gathers FOUR neighbor rows (16 lanes x 16B = 256B row per group). Two loads per
// j-step = 8 rows in flight per 2 instructions. Cross-group butterfly combines at the end.
__global__ __launch_bounds__(256) void k_agg(const __half* __restrict__ XW, const int* __restrict__ cs,
                                             const int* __restrict__ rp, const float* __restrict__ dinv,
                                             const float* __restrict__ bias, __half* __restrict__ Hn, int n) {
    int wid  = (blockIdx.x * 256 + threadIdx.x) >> 6;
    int lane = threadIdx.x & 63;
    if (wid >= n) return;
    int s = rp[wid], e = rp[wid + 1];
    const int g = lane >> 4, fs = lane & 15;
    float acc0[8], acc1[8];
#pragma unroll
    for (int k = 0; k < 8; ++k) { acc0[k] = 0.f; acc1[k] = 0.f; }
    for (int base = s; base < e; base += 64) {
        int m = e - base;
        if (m > 64) m = 64;
        int myi = (lane < m) ? cs[base + lane] : 0;
#pragma unroll 2
        for (int j = 0; j < m; j += 8) {
            int ia = __shfl(myi, j + g);
            int ib = __shfl(myi, j + 4 + g);
            if (j + g < m) {
                f16x8 va = *(const f16x8*)&XW[(size_t)ia * 128 + fs * 8];
#pragma unroll
                for (int k = 0; k < 8; ++k) acc0[k] += (float)va[k];
            }
            if (j + 4 + g < m) {
                f16x8 vb = *(const f16x8*)&XW[(size_t)ib * 128 + fs * 8];
#pragma unroll
                for (int k = 0; k < 8; ++k) acc1[k] += (float)vb[k];
            }
        }
    }
#pragma unroll
    for (int k = 0; k < 8; ++k) acc0[k] += acc1[k];
#pragma unroll
    for (int k = 0; k < 8; ++k) acc0[k] += __shfl_xor(acc0[k], 16);
#pragma unroll
    for (int k = 0; k < 8; ++k) acc0[k] += __shfl_xor(acc0[k], 32);
    if (g == 0) {
        float dvv = dinv[wid];
        float4 bb0 = *(const float4*)&bias[fs * 8];
        float4 bb1 = *(const float4*)&bias[fs * 8 + 4];
        float bb[8] = {bb0.x, bb0.y, bb0.z, bb0.w, bb1.x, bb1.y, bb1.z, bb1.w};
        f16x8 o;
#pragma unroll
        for (int k = 0; k < 8; ++k)
            o[k] = (_Float16)fmaxf(fmaf(acc0[k], dvv, bb[k]), 0.f);
        *(f16x8*)&Hn[(size_t)wid * 128 + fs * 8] = o;
    }
}

// ================= fused pooling + head: one block per graph =================
__global__ __launch_bounds__(256) void k_poolhead(const __half* __restrict__ H, const int* __restrict__ batch,
                                                  const float* __restrict__ w1, const float* __restrict__ b1,
                                                  const float* __restrict__ w2, const float* __restrict__ b2,
                                                  float* __restrict__ out, int n) {
    __shared__ float lsum[16][128];
    __shared__ float lmax[16][128];
    __shared__ float gv[384];
    __shared__ float o1[128];
    __shared__ int bnd[2];
    int g = blockIdx.x, t = threadIdx.x;
    if (t < 2) {
        int key = g + t;
        int lo = 0, hi = n;
        while (lo < hi) {
            int mid = (lo + hi) >> 1;
            if (batch[mid] < key) lo = mid + 1; else hi = mid;
        }
        bnd[t] = lo;
    }
    __syncthreads();
    const int s = bnd[0], e = bnd[1];
    const int rg = t >> 4, fb = t & 15;
    float sum8[8], max8[8];
#pragma unroll
    for (int j = 0; j < 8; ++j) { sum8[j] = 0.f; max8[j] = 0.f; }  // h>=0: 0-init == isfinite guard
    for (int r = s + rg; r < e; r += 16) {
        f16x8 v = *(const f16x8*)&H[(size_t)r * 128 + fb * 8];
#pragma unroll
        for (int j = 0; j < 8; ++j) {
            float x = (float)v[j];
            sum8[j] += x;
            max8[j] = fmaxf(max8[j], x);
        }
    }
#pragma unroll
    for (int j = 0; j < 8; ++j) {
        lsum[rg][fb * 8 + j] = sum8[j];
        lmax[rg][fb * 8 + j] = max8[j];
    }
    __syncthreads();
    if (t < 128) {
        float sum = 0.f, mx = 0.f;
#pragma unroll
        for (int r = 0; r < 16; ++r) {
            sum += lsum[r][t];
            mx = fmaxf(mx, lmax[r][t]);
        }
        float cnt = (float)(e - s);
        gv[t]       = sum;
        gv[128 + t] = sum / fmaxf(cnt, 1.f);
        gv[256 + t] = mx;
    }
    __syncthreads();
    if (t < 128) {
        float acc = b1[t];
#pragma unroll 8
        for (int k = 0; k < 384; ++k) acc = fmaf(gv[k], w1[k * 128 + t], acc);
        o1[t] = fmaxf(acc, 0.f);
    }
    __syncthreads();
    if (t < 64) {
        float p0 = o1[t] * w2[t * 2 + 0] + o1[t + 64] * w2[(t + 64) * 2 + 0];
        float p1 = o1[t] * w2[t * 2 + 1] + o1[t + 64] * w2[(t + 64) * 2 + 1];
        for (int off = 32; off > 0; off >>= 1) {
            p0 += __shfl_down(p0, off);
            p1 += __shfl_down(p1, off);
        }
        if (t == 0) {
            float l0 = p0 + b2[0], l1 = p1 + b2[1];
            float m = fmaxf(l0, l1);
            float lse = m + logf(expf(l0 - m) + expf(l1 - m));
            out[g * 2 + 0] = l0 - lse;
            out[g * 2 + 1] = l1 - lse;
        }
    }
}

// ================= launcher =================

extern "C" void kernel_launch(void* const* d_in, const int* in_sizes, int n_in,
                              void* d_out, int out_size, void* d_ws, size_t ws_size,
                              hipStream_t stream) {
    const float* x     = (const float*)d_in[0];
    const int*   ei    = (const int*)d_in[1];
    const int*   batch = (const int*)d_in[2];
    const float* W0    = (const float*)d_in[3];
    const float* b0    = (const float*)d_in[4];
    const float* Wh    = (const float*)d_in[5];
    const float* bh    = (const float*)d_in[6];
    const float* l1w   = (const float*)d_in[7];
    const float* l1b   = (const float*)d_in[8];
    const float* l2w   = (const float*)d_in[9];
    const float* l2b   = (const float*)d_in[10];
    float* out = (float*)d_out;

    const int N  = in_sizes[0] / 128;
    const int E  = in_sizes[1] / 2;
    const int G  = out_size / 2;
    const int LX = in_sizes[5] / (128 * 128);
    const int NB = (N + 255) / 256;  // buckets (<=256 assumed, N<=65536)

    const int* src = ei;
    const int* dst = ei + E;

    char* p = (char*)d_ws;
    auto alloc = [&](size_t bytes) -> void* {
        void* r = (void*)p;
        p += (bytes + 255) & ~(size_t)255;
        return r;
    };
    int*    rowptr = (int*)alloc((size_t)(N + 1) * 4);
    float*  dinv   = (float*)alloc((size_t)N * 4);
    int*    bcnt   = (int*)alloc(1040);
    int*    bebase = (int*)alloc(1040);
    int*    bcbase = (int*)alloc(1040);
    int*    bcur   = (int*)alloc(1040);
    int*    csr_s  = (int*)alloc((size_t)(E + N) * 4);
    int*    bedges = (int*)alloc((size_t)E * 4);
    __half* h16    = (__half*)alloc((size_t)N * 128 * 2);
    __half* xw16   = (__half*)alloc((size_t)N * 128 * 2);
    __half* wp     = (__half*)alloc((size_t)(LX + 1) * 16384 * 2);

    // --- weight pack (+ bcnt zero) ---
    k_wprep<<<LX + 2, 256, 0, stream>>>(W0, Wh, wp, bcnt, LX + 1);

    // --- bucketed CSR setup (once per launch, reused by all layers) ---
    k_bhist<<<NB, 256, 0, stream>>>(dst, bcnt, E);
    k_bscan<<<1, 256, 0, stream>>>(bcnt, bebase, bcbase, bcur, rowptr, NB, N, E);
    k_bscatter<<<(E + 4095) / 4096, 256, 0, stream>>>(src, dst, bcur, bedges, E);
    k_bcsr<<<NB, 256, 0, stream>>>(bedges, bebase, bcbase, rowptr, dinv, csr_s, N);

    // --- 4 GCN layers ---
    const int gemmBlocks = (N + 127) / 128;
    const int aggBlocks  = (N + 3) / 4;

    k_gemm32<<<gemmBlocks, 256, 0, stream>>>(x, wp, dinv, xw16, N);
    k_agg<<<aggBlocks, 256, 0, stream>>>(xw16, csr_s, rowptr, dinv, b0, h16, N);
    for (int l = 0; l < LX; ++l) {
        k_gemm<<<gemmBlocks, 256, 0, stream>>>(h16, wp + (size_t)(l + 1) * 16384, dinv, xw16, N);
        k_agg<<<aggBlocks, 256, 0, stream>>>(xw16, csr_s, rowptr, dinv, bh + (size_t)l * 128, h16, N);
    }

    // --- fused pooling + head ---
    k_poolhead<<<G, 256, 0, stream>>>(h16, batch, l1w, l1b, l2w, l2b, out, N);
}